// Round 12
// baseline (538.038 us; speedup 1.0000x reference)
//
#include <hip/hip_runtime.h>
#include <math.h>

// ---------------------------------------------------------------------------
// xLSTM decoder block, MI355X gfx950.
// R20 = exact revert to R18 (best measured: 437.7us). R19's BM=64 gemm2 +
// lambda GEMM refactor regressed ~13us machine-equivalent (tail calibration:
// that acquire ran 13% slow; tail 100->113us with identical code).
// Pipeline (all flat (b*12+ch)*1024+l layout):
//  prep:   ONE merged kernel: Wg/upl/upr/down bf16 transposes (WupT 16-col
//          interleaved so gemm3's epilogue holds l/r of the same logical
//          column), 4 dispatches merged into 1 via job table.
//  ln_fc:  FUSED ln1 + fc1(conv k3) + fc2(1x1) + ln2.
//  gemm0:  xn2 @ WgT + bg -> gx (bf16, 6144x4096)
//  rec:    MFMA sLSTM per (head, 16 batches), T14 next-step gx prefetch.
//  gemm3:  hn @ WupT(ilv) -> fused gate epilogue: glr = gelu(l)*r
//  gemm2:  glr @ WdT + down_b ; epilogue y = silu(xc)*(acc+b+x1)+xn -> yb
//  tail:   FUSED conv1+gelu+LN(len)+conv2+skip (R16 2-half structure,
//          ~100us plateau — latency-bound at grid-pinned 2 blocks/CU).
//  GEMM: 2-phase dbuf macro form, linear LDS (R17 swizzle and R19 BM=64
//  both regressed — this structure is the measured optimum).
// ---------------------------------------------------------------------------

typedef short short8_t __attribute__((ext_vector_type(8)));
typedef float floatx4 __attribute__((ext_vector_type(4)));
typedef float float2_t __attribute__((ext_vector_type(2)));

typedef unsigned int u32;
typedef const __attribute__((address_space(1))) u32 gu32;
typedef __attribute__((address_space(3))) u32 lu32;

static __device__ __forceinline__ float b2f(unsigned short u) {
    unsigned v = ((unsigned)u) << 16;
    return __builtin_bit_cast(float, v);
}
static __device__ __forceinline__ unsigned short f2b(float f) {
    unsigned u = __builtin_bit_cast(unsigned, f);
    u += 0x7FFFu + ((u >> 16) & 1u);   // RNE
    return (unsigned short)(u >> 16);
}
static __device__ __forceinline__ float2_t make2u(unsigned u) {
    float2_t r;
    r.x = __builtin_bit_cast(float, u << 16);
    r.y = __builtin_bit_cast(float, u & 0xFFFF0000u);
    return r;
}
static __device__ __forceinline__ u32 pack2(float a, float b) {
    return ((u32)f2b(b) << 16) | (u32)f2b(a);
}
// tanh-form gelu in sigmoid shape: x*sigma(2u) == 0.5x(1+tanh(u)).
static __device__ __forceinline__ float gelu_fast(float x) {
    float u = 0.7978845608f * x * (1.f + 0.044715f * x * x);
    u = fminf(fmaxf(u, -9.f), 9.f);
    return x * __builtin_amdgcn_rcpf(1.f + __expf(-2.f * u));
}

// --------------------------- weight prep (merged) --------------------------
// One dispatch, 4 jobs selected by blockIdx.x range. All jobs have K=1024
// (grid.y = 32). dst row = (n>>4)*GS + GO + (n&15).
//   job0: bx [  0,128) Wg   -> WgT  N=4096 GS=16 GO=0
//   job1: bx [128,160) upl  -> WupT N=1024 GS=32 GO=0
//   job2: bx [160,192) upr  -> WupT N=1024 GS=32 GO=16
//   job3: bx [192,224) down -> WdT  N=1024 GS=16 GO=0

__global__ __launch_bounds__(256) void prep_weights_kernel(
    const float* __restrict__ Wg, const float* __restrict__ upl,
    const float* __restrict__ upr, const float* __restrict__ down,
    unsigned short* __restrict__ WgT, unsigned short* __restrict__ WupT,
    unsigned short* __restrict__ WdT)
{
    __shared__ unsigned short tl[32][33];
    const int bx = blockIdx.x;
    const float* src;
    unsigned short* dst;
    int N, GS, GO, n0;
    if (bx < 128)      { src = Wg;   dst = WgT;  N = 4096; GS = 16; GO = 0;  n0 = bx * 32; }
    else if (bx < 160) { src = upl;  dst = WupT; N = 1024; GS = 32; GO = 0;  n0 = (bx - 128) * 32; }
    else if (bx < 192) { src = upr;  dst = WupT; N = 1024; GS = 32; GO = 16; n0 = (bx - 160) * 32; }
    else               { src = down; dst = WdT;  N = 1024; GS = 16; GO = 0;  n0 = (bx - 192) * 32; }
    const int K = 1024;
    const int k0 = blockIdx.y * 32;
    const int tx = threadIdx.x & 31, ty = threadIdx.x >> 5;
#pragma unroll
    for (int r = 0; r < 4; r++) {
        int k = ty + r * 8;
        tl[tx][k] = f2b(src[(size_t)(k0 + k) * N + n0 + tx]);
    }
    __syncthreads();
#pragma unroll
    for (int r = 0; r < 4; r++) {
        int n = n0 + ty * 4 + r;
        size_t row = (size_t)((n >> 4) * GS + GO + (n & 15));
        dst[row * K + k0 + tx] = tl[ty * 4 + r][tx];
    }
}

__global__ __launch_bounds__(256) void bias_ilv_kernel(
    const float* __restrict__ bl, const float* __restrict__ br,
    float* __restrict__ o)
{   // o[2048] interleaved to match WupT rows
    int i = blockIdx.x * 256 + threadIdx.x;
    int grp = i >> 5, w = i & 31;
    o[i] = (w < 16) ? bl[grp * 16 + w] : br[grp * 16 + (w - 16)];
}

// ---- FUSED ln1 + fc1 (conv k3) + fc2 (1x1) + ln2 --------------------------

__global__ __launch_bounds__(512, 2) void ln_fc_kernel(
    const float* __restrict__ x,
    const float* __restrict__ g, const float* __restrict__ be,
    const float* __restrict__ xlg, const float* __restrict__ xlb,
    const float* __restrict__ w1, const float* __restrict__ b1,
    const float* __restrict__ w2, const float* __restrict__ b2,
    float* __restrict__ xn, unsigned short* __restrict__ xcb,
    unsigned short* __restrict__ x1b, unsigned short* __restrict__ xn2b)
{
    __shared__ float sX[12][1028];   // 49.3 KB
    __shared__ float sMR[12][2];
    const int b = blockIdx.x;
    const int t = threadIdx.x;
    const int p = t;                 // positions p, p+512
    const size_t boff = (size_t)b * 12288;

    if (t < 12) { sX[t][0] = 0.f; sX[t][1025] = 0.f; sX[t][1026] = 0.f; sX[t][1027] = 0.f; }
    {
        const float* gx = x + boff;
#pragma unroll
        for (int ci = 0; ci < 12; ci++) {
            sX[ci][1 + p] = gx[ci * 1024 + p];
            sX[ci][1 + p + 512] = gx[ci * 1024 + p + 512];
        }
    }
    __syncthreads();

    // ---- LN1 stats: wave wv handles ch wv, and ch 8+wv for wv<4
    {
        const int wv = t >> 6, la = t & 63;
#pragma unroll
        for (int j = 0; j < 2; j++) {
            const int ch = wv + j * 8;
            if (ch < 12) {
                float s = 0.f, ss = 0.f;
#pragma unroll
                for (int u = 0; u < 16; u++) {
                    float v = sX[ch][1 + la + u * 64];
                    s += v; ss += v * v;
                }
#pragma unroll
                for (int off = 32; off >= 1; off >>= 1) {
                    s += __shfl_xor(s, off);
                    ss += __shfl_xor(ss, off);
                }
                if (la == 0) {
                    float mu = s * (1.f / 1024.f);
                    float var = ss * (1.f / 1024.f) - mu * mu;
                    sMR[ch][0] = mu;
                    sMR[ch][1] = rsqrtf(var + 1e-5f);
                }
            }
        }
    }
    __syncthreads();

    // ---- normalize in place + write xn (skip)
    const float gA = g[p], bA = be[p];
    const float gB = g[p + 512], bB = be[p + 512];
#pragma unroll
    for (int ch = 0; ch < 12; ch++) {
        const float mu = sMR[ch][0], rs = sMR[ch][1];
        float v0 = (sX[ch][1 + p] - mu) * rs * gA + bA;
        float v1 = (sX[ch][1 + p + 512] - mu) * rs * gB + bB;
        sX[ch][1 + p] = v0;
        sX[ch][1 + p + 512] = v1;
        xn[boff + (size_t)ch * 1024 + p] = v0;
        xn[boff + (size_t)ch * 1024 + p + 512] = v1;
    }
    __syncthreads();

    // ---- conv1 (k=3): ci-outer, packed pairs
    float2_t a1[12];
#pragma unroll
    for (int o = 0; o < 12; o++) { float bv = b1[o]; a1[o] = float2_t{bv, bv}; }
    for (int ci = 0; ci < 12; ci++) {
        float2_t vm = float2_t{sX[ci][p],     sX[ci][p + 512]};
        float2_t v0 = float2_t{sX[ci][p + 1], sX[ci][p + 513]};
        float2_t vp = float2_t{sX[ci][p + 2], sX[ci][p + 514]};
        const float* wp = w1 + ci * 3;               // uniform -> SGPR
#pragma unroll
        for (int o = 0; o < 12; o++) {
            const float* wo = wp + o * 36;
            a1[o] += vm * wo[0] + v0 * wo[1] + vp * wo[2];
        }
    }
    __syncthreads();   // all tap reads of sX complete before reuse

#pragma unroll
    for (int o = 0; o < 12; o++) {
        xcb[boff + (size_t)o * 1024 + p] = f2b(a1[o].x);
        xcb[boff + (size_t)o * 1024 + p + 512] = f2b(a1[o].y);
    }

    // ---- fc2 (1x1); stash x1 into sX for LN2 stats
    float2_t a2[12];
#pragma unroll
    for (int o = 0; o < 12; o++) { float bv = b2[o]; a2[o] = float2_t{bv, bv}; }
#pragma unroll
    for (int ci = 0; ci < 12; ci++) {
#pragma unroll
        for (int o = 0; o < 12; o++)
            a2[o] += a1[ci] * w2[o * 12 + ci];
    }
#pragma unroll
    for (int o = 0; o < 12; o++) {
        x1b[boff + (size_t)o * 1024 + p] = f2b(a2[o].x);
        x1b[boff + (size_t)o * 1024 + p + 512] = f2b(a2[o].y);
        sX[o][p] = a2[o].x;
        sX[o][p + 512] = a2[o].y;
    }
    __syncthreads();

    // ---- LN2 stats (plain columns 0..1023)
    {
        const int wv = t >> 6, la = t & 63;
#pragma unroll
        for (int j = 0; j < 2; j++) {
            const int ch = wv + j * 8;
            if (ch < 12) {
                float s = 0.f, ss = 0.f;
#pragma unroll
                for (int u = 0; u < 16; u++) {
                    float v = sX[ch][la + u * 64];
                    s += v; ss += v * v;
                }
#pragma unroll
                for (int off = 32; off >= 1; off >>= 1) {
                    s += __shfl_xor(s, off);
                    ss += __shfl_xor(ss, off);
                }
                if (la == 0) {
                    float mu = s * (1.f / 1024.f);
                    float var = ss * (1.f / 1024.f) - mu * mu;
                    sMR[ch][0] = mu;
                    sMR[ch][1] = rsqrtf(var + 1e-5f);
                }
            }
        }
    }
    __syncthreads();

    // ---- LN2 normalize from registers -> xn2b bf16
    const float xgA = xlg[p], xbA = xlb[p];
    const float xgB = xlg[p + 512], xbB = xlb[p + 512];
#pragma unroll
    for (int ch = 0; ch < 12; ch++) {
        const float mu = sMR[ch][0], rs = sMR[ch][1];
        xn2b[boff + (size_t)ch * 1024 + p] =
            f2b((a2[ch].x - mu) * rs * xgA + xbA);
        xn2b[boff + (size_t)ch * 1024 + p + 512] =
            f2b((a2[ch].y - mu) * rs * xgB + xbB);
    }
}

// ------------------------------ bf16 GEMM ----------------------------------
// MODE 0: store bf16.
// MODE 2: y = silu(xc)*(acc+bias+x1) + skip, store bf16 (xc/x1 bf16).
// MODE 3: fused up-gate: B is 16-col interleaved [l|r]; out (N/2 cols) =
//         gelu(l + bias_l) * (r + bias_r), store bf16.
// 2-phase double-buffered K-loop (R16/R18 macro form — linear LDS).

template <int MODE>
__global__ __launch_bounds__(256) void gemm_kernel(
    const unsigned short* __restrict__ A, const unsigned short* __restrict__ BT,
    const float* __restrict__ bias, void* __restrict__ out,
    int M, int N, int K,
    const unsigned short* __restrict__ xcb, const unsigned short* __restrict__ x1b,
    const float* __restrict__ skip)
{
    __shared__ __align__(16) unsigned short sA[2][128 * 32];  // 8 KB x2
    __shared__ __align__(16) unsigned short sB[2][128 * 32];
    const int t = threadIdx.x;
    const int m0 = blockIdx.y * 128;
    const int n0 = blockIdx.x * 128;
    const int w = t >> 6;
    const int lane = t & 63;
    const int wr = (w >> 1) * 64;
    const int wc = (w & 1) * 64;
    const int lrow = lane & 15;
    const int quad = lane >> 4;
    const int row_l = t >> 2;
    const int cs = (t & 3) * 8;

    const unsigned short* gA0 = A + (size_t)(m0 + row_l) * K + cs;
    const unsigned short* gA1 = A + (size_t)(m0 + row_l + 64) * K + cs;
    const unsigned short* gB0 = BT + (size_t)(n0 + row_l) * K + cs;
    const unsigned short* gB1 = BT + (size_t)(n0 + row_l + 64) * K + cs;

    floatx4 acc[4][4];
#pragma unroll
    for (int i = 0; i < 4; i++)
#pragma unroll
        for (int j = 0; j < 4; j++) acc[i][j] = (floatx4)0.f;

#define GEMM_STAGE(buf, k0)                                                        \
    do {                                                                           \
        __builtin_amdgcn_global_load_lds((gu32*)(gA0 + (k0)),                      \
            (lu32*)(&sA[buf][w * 512]), 16, 0, 0);                                 \
        __builtin_amdgcn_global_load_lds((gu32*)(gA1 + (k0)),                      \
            (lu32*)(&sA[buf][2048 + w * 512]), 16, 0, 0);                          \
        __builtin_amdgcn_global_load_lds((gu32*)(gB0 + (k0)),                      \
            (lu32*)(&sB[buf][w * 512]), 16, 0, 0);                                 \
        __builtin_amdgcn_global_load_lds((gu32*)(gB1 + (k0)),                      \
            (lu32*)(&sB[buf][2048 + w * 512]), 16, 0, 0);                          \
    } while (0)

#define GEMM_COMPUTE(buf)                                                          \
    do {                                                                           \
        short8_t af[4], bfr[4];                                                    \
        _Pragma("unroll")                                                          \
        for (int i = 0; i < 4; i++) {                                              \
            af[i] = *(const short8_t*)(&sA[buf][(wr + i * 16 + lrow) * 32 + quad * 8]); \
            bfr[i] = *(const short8_t*)(&sB[buf][(wc + i * 16 + lrow) * 32 + quad * 8]); \
        }                                                                          \
        _Pragma("unroll")                                                          \
        for (int i = 0; i < 4; i++)                                                \
            _Pragma("unroll")                                                      \
            for (int j = 0; j < 4; j++)                                            \
                acc[i][j] = __builtin_amdgcn_mfma_f32_16x16x32_bf16(               \
                    af[i], bfr[j], acc[i][j], 0, 0, 0);                            \
    } while (0)

    GEMM_STAGE(0, 0);
    __syncthreads();
    int cur = 0;
    for (int k0 = 32; k0 < K; k0 += 32) {
        GEMM_STAGE(cur ^ 1, k0);   // issue next tile
        GEMM_COMPUTE(cur);         // compute current
        __syncthreads();           // drains vmcnt; protects buffer reuse
        cur ^= 1;
    }
    GEMM_COMPUTE(cur);             // last tile

#undef GEMM_STAGE
#undef GEMM_COMPUTE

    if (MODE == 3) {
#pragma unroll
        for (int i = 0; i < 4; i++) {
#pragma unroll
            for (int k = 0; k < 2; k++) {
#pragma unroll
                for (int r = 0; r < 4; r++) {
                    const int gm = m0 + wr + i * 16 + quad * 4 + r;
                    const int pl = n0 + wc + k * 32 + lrow;   // physical l col
                    float lv = acc[i][2 * k][r] + bias[pl];
                    float rv = acc[i][2 * k + 1][r] + bias[pl + 16];
                    const int nlog = (pl >> 5) * 16 + lrow;
                    ((unsigned short*)out)[(size_t)gm * (N >> 1) + nlog] =
                        f2b(gelu_fast(lv) * rv);
                }
            }
        }
    } else {
#pragma unroll
        for (int i = 0; i < 4; i++) {
#pragma unroll
            for (int j = 0; j < 4; j++) {
#pragma unroll
                for (int r = 0; r < 4; r++) {
                    const int gm = m0 + wr + i * 16 + quad * 4 + r;
                    const int gn = n0 + wc + j * 16 + lrow;
                    const size_t idx = (size_t)gm * N + gn;
                    float v = acc[i][j][r] + bias[gn];
                    if (MODE == 0) {
                        ((unsigned short*)out)[idx] = f2b(v);
                    } else {
                        float xcv = b2f(xcb[idx]);
                        float sig = xcv * __builtin_amdgcn_rcpf(1.f + __expf(-xcv));
                        ((unsigned short*)out)[idx] =
                            f2b(sig * (v + b2f(x1b[idx])) + skip[idx]);
                    }
                }
            }
        }
    }
}

// ------------------- sLSTM recurrence + GroupNorm (MFMA) -------------------
// grid (NH=8, B/16=32) = 256 blocks (1/CU), block 1024 (16 waves, 4/SIMD).
// T14 prefetch: next step's gx loads issued right after the MFMA.

#define RECP 516   // f32 row stride for sRec (2-way bank aliasing only)
#define HBP  136   // bf16 row stride for sHb

__global__ __launch_bounds__(1024, 1) void slstm_rec_kernel(
    const float* __restrict__ Rg,             // [8][512][128] f32
    const unsigned short* __restrict__ gxb,   // [B][12][4096] bf16
    const float* __restrict__ gn_g, const float* __restrict__ gn_b,
    unsigned short* __restrict__ hnb)         // [B][12][1024] bf16
{
    __shared__ __align__(16) float sRec[16 * RECP];
    __shared__ __align__(16) unsigned short sHb[16 * HBP];
    const int head = blockIdx.x;
    const int b0 = blockIdx.y * 16;
    const int t = threadIdx.x;
    const int w = t >> 6;
    const int lane = t & 63;
    const int quad = lane >> 4;
    const int l16 = lane & 15;

    short8_t Bf[2][4];
    {
        const float* Rh = Rg + (size_t)head * 65536;
#pragma unroll
        for (int jt = 0; jt < 2; jt++)
#pragma unroll
            for (int kk = 0; kk < 4; kk++) {
                const float* src =
                    Rh + (size_t)(w * 32 + jt * 16 + l16) * 128 + kk * 32 + quad * 8;
                short8_t v;
#pragma unroll
                for (int j = 0; j < 8; j++) v[j] = (short)f2b(src[j]);
                Bf[jt][kk] = v;
            }
    }

    for (int i = t; i < 16 * HBP; i += 1024) sHb[i] = 0;

    const int la = lane;
    float c0 = 0.f, n0s = 0.f, m0 = 0.f;
    float c1 = 0.f, n1s = 0.f, m1 = 0.f;
    const float gg0 = gn_g[head * 128 + la];
    const float gg1 = gn_g[head * 128 + la + 64];
    const float gb0 = gn_b[head * 128 + la];
    const float gb1 = gn_b[head * 128 + la + 64];

    const unsigned short* gbase = gxb + (size_t)(b0 + w) * 12 * 4096 + head * 512;
    float gv[8];
#pragma unroll
    for (int q = 0; q < 8; q++) gv[q] = b2f(gbase[q * 64 + la]);   // step 0

    __syncthreads();

    for (int step = 0; step < 12; step++) {
        float gz0 = gv[0], gz1 = gv[1];
        float gi0 = gv[2], gi1 = gv[3];
        float gf0 = gv[4], gf1 = gv[5];
        float go0 = gv[6], go1 = gv[7];

        short8_t Af[4];
#pragma unroll
        for (int kk = 0; kk < 4; kk++)
            Af[kk] = *(const short8_t*)(sHb + l16 * HBP + kk * 32 + quad * 8);
        floatx4 D0 = (floatx4)0.f, D1 = (floatx4)0.f;
#pragma unroll
        for (int kk = 0; kk < 4; kk++) {
            D0 = __builtin_amdgcn_mfma_f32_16x16x32_bf16(Af[kk], Bf[0][kk], D0, 0, 0, 0);
            D1 = __builtin_amdgcn_mfma_f32_16x16x32_bf16(Af[kk], Bf[1][kk], D1, 0, 0, 0);
        }

        // ---- prefetch next step's gx (clamped index; unused at step 11).
        {
            const int sn = (step < 11) ? step + 1 : step;
            const unsigned short* gpn = gbase + (size_t)sn * 4096;
#pragma unroll
            for (int q = 0; q < 8; q++) gv[q] = b2f(gpn[q * 64 + la]);
        }

#pragma unroll
        for (int r = 0; r < 4; r++) {
            sRec[(quad * 4 + r) * RECP + w * 32 + l16] = D0[r];
            sRec[(quad * 4 + r) * RECP + w * 32 + 16 + l16] = D1[r];
        }
        __syncthreads();

        const float* rr = sRec + w * RECP;
        float zp0 = gz0 + rr[la],       zp1 = gz1 + rr[64 + la];
        float ip0 = gi0 + rr[128 + la], ip1 = gi1 + rr[192 + la];
        float fp0 = gf0 + rr[256 + la], fp1 = gf1 + rr[320 + la];
        float op0 = go0 + rr[384 + la], op1 = go1 + rr[448 + la];

        // tanh via sigmoid form + v_rcp (graceful at +/-inf preacts)
        float e20 = __expf(-2.f * zp0), e21 = __expf(-2.f * zp1);
        float z0 = 2.f * __builtin_amdgcn_rcpf(1.f + e20) - 1.f;
        float z1 = 2.f * __builtin_amdgcn_rcpf(1.f + e21) - 1.f;
        float o0 = __builtin_amdgcn_rcpf(1.f + __expf(-op0));
        float o1 = __builtin_amdgcn_rcpf(1.f + __expf(-op1));
        float mn0 = fmaxf(fp0 + m0, ip0), mn1 = fmaxf(fp1 + m1, ip1);
        float ie0 = __expf(ip0 - mn0), ie1 = __expf(ip1 - mn1);
        float fe0 = __expf(fp0 + m0 - mn0), fe1 = __expf(fp1 + m1 - mn1);
        c0 = fe0 * c0 + ie0 * z0;  c1 = fe1 * c1 + ie1 * z1;
        n0s = fe0 * n0s + ie0;     n1s = fe1 * n1s + ie1;
        m0 = mn0;                  m1 = mn1;
        float h0 = o0 * c0 * __builtin_amdgcn_rcpf(n0s);
        float h1 = o1 * c1 * __builtin_amdgcn_rcpf(n1s);

        float s = h0 + h1, ss = h0 * h0 + h1 * h1;
#pragma unroll
        for (int off = 32; off >= 1; off >>= 1) {
            s += __shfl_xor(s, off);
            ss += __shfl_xor(ss, off);
        }
        float mu = s * (1.f / 128.f);
        float var = ss * (1.f / 128.f) - mu * mu;
        float rs = rsqrtf(var + 1e-5f);
        size_t base = ((size_t)(b0 + w) * 12 + step) * 1024 + head * 128;
        hnb[base + la] = f2b((h0 - mu) * rs * gg0 + gb0);
        hnb[base + la + 64] = f2b((h1 - mu) * rs * gg1 + gb1);

        sHb[w * HBP + la] = f2b(h0);
        sHb[w * HBP + la + 64] = f2b(h1);
        __syncthreads();
    }
}

// ---------------- fused tail: conv1+gelu+LN(len)+conv2+skip ----------------
// R16 2-half structure (measured ~100us, VGPR 56, no spill).

__global__ __launch_bounds__(512, 2) void tail_fused_kernel(
    const unsigned short* __restrict__ y, const float* __restrict__ skip,
    const float* __restrict__ w1, const float* __restrict__ b1,
    const float* __restrict__ w2, const float* __restrict__ b2,
    const float* __restrict__ lng, const float* __restrict__ lnb,
    float* __restrict__ out)
{
    __shared__ unsigned short sY[12][1026];   // 24.6 KB
    __shared__ unsigned short sZ[24][1026];   // 49.2 KB
    __shared__ float sMR[24][2];
    const int b = blockIdx.x;
    const int t = threadIdx.x;
    const int p = t;                          // positions p, p+512
    const size_t boff = (size_t)b * 12288;

    {
        const u32* gy = (const u32*)(y + boff);
#pragma unroll
        for (int ci = 0; ci < 12; ci++)
            ((u32*)&sY[ci][0])[t] = gy[ci * 512 + t];
    }
    // LN gains for the dword-mapped normalize pass (positions 2t, 2t+1)
    const float lgA = lng[2 * t], lbA = lnb[2 * t];
    const float lgB = lng[2 * t + 1], lbB = lnb[2 * t + 1];
    __syncthreads();

    float2_t acc[12];
#pragma unroll
    for (int o = 0; o < 12; o++) { float bv = b2[o]; acc[o] = float2_t{bv, bv}; }

    for (int h = 0; h < 2; h++) {
        // ---- conv1: 12 in -> this half's 24 out channels, ci-outer
        float2_t a1[24];
#pragma unroll
        for (int o = 0; o < 24; o++) {
            float bo = b1[h * 24 + o];
            a1[o] = float2_t{bo, bo};
        }
        for (int ci = 0; ci < 12; ci++) {
            float2_t v0 = float2_t{b2f(sY[ci][p]), b2f(sY[ci][p + 512])};
            float2_t vm = float2_t{(p > 0) ? b2f(sY[ci][p - 1]) : 0.f,
                                   b2f(sY[ci][p + 511])};
            float2_t vp = float2_t{b2f(sY[ci][p + 1]),
                                   (p < 511) ? b2f(sY[ci][p + 513]) : 0.f};
            const float* wp = w1 + ci * 3;             // uniform -> SGPR
#pragma unroll
            for (int o = 0; o < 24; o++) {
                const float* wo = wp + (h * 24 + o) * 36;
                a1[o] += vm * wo[0] + v0 * wo[1] + vp * wo[2];
            }
        }
#pragma unroll
        for (int o = 0; o < 24; o++) {
            sZ[o][p] = f2b(gelu_fast(a1[o].x));
            sZ[o][p + 512] = f2b(gelu_fast(a1[o].y));
        }
        __syncthreads();

        // ---- LN stats: wave wv handles ch wv, wv+8, wv+16
        {
            const int wv = t >> 6, la = t & 63;
#pragma unroll
            for (int j = 0; j < 3; j++) {
                const int ch = wv + j * 8;
                float s = 0.f, ss = 0.f;
#pragma unroll
                for (int u = 0; u < 8; u++) {
                    float2_t v = make2u(((const u32*)&sZ[ch][0])[la + u * 64]);
                    s += v.x + v.y;
                    ss += v.x * v.x + v.y * v.y;
                }
#pragma unroll
                for (int off = 32; off >= 1; off >>= 1) {
                    s += __shfl_xor(s, off);
                    ss += __shfl_xor(ss, off);
                }
                if (la == 0) {
                    float mu = s * (1.f / 1024.f);
                    float var = ss * (1.f / 1024.f) - mu * mu;
                    sMR[ch][0] = mu;
                    sMR[ch][1] = rsqrtf(var + 1e-5f);
                }
            }
        }
        __syncthreads();

        // ---- normalize in place (dword mapping: one b32 read+write per ch)
#pragma unroll
        for (int ch = 0; ch < 24; ch++) {
            const float mu = sMR[ch][0], rs = sMR[ch][1];
            float2_t f = make2u(((const u32*)&sZ[ch][0])[t]);
            f.x = (f.x - mu) * rs * lgA + lbA;
            f.y = (f.y - mu) * rs * lgB + lbB;
            ((u32*)&sZ[ch][0])[t] = pack2(f.x, f.y);
        }
        __syncthreads();

        // ---- conv2 partial over this half's 24 input channels
        for (int ci = 0; ci < 24; ci++) {
            float2_t z0 = float2_t{b2f(sZ[ci][p]), b2f(sZ[ci][p + 512])};
            float2_t zm = float2_t{(p > 0) ? b2f(sZ[ci][p - 1]) : 0.f,
                                   b2f(sZ[ci][p + 511])};
            float2_t zp = float2_t{b2f(sZ[ci][p + 1]),
                                   (p < 511) ? b2f(sZ[ci][p + 513]) : 0.f};
            const float* wp = w2 + (h * 24 + ci) * 3;  // uniform -> SGPR
#pragma unroll
            for (int o = 0; o < 12; o++)
                acc[o] += zm * wp[o * 144] + z0 * wp[o * 144 + 1]
                        + zp * wp[o * 144 + 2];
        }
        __syncthreads();   // before next half overwrites sZ
    }

#pragma unroll
    for (int o = 0; o < 12; o++) {
        size_t i0 = boff + (size_t)o * 1024 + p;
        out[i0] = acc[o].x + skip[i0];
        out[i0 + 512] = acc[o].y + skip[i0 + 512];
    }
}

// ------------------------------ launcher -----------------------------------

extern "C" void kernel_launch(void* const* d_in, const int* in_sizes, int n_in,
                              void* d_out, int out_size, void* d_ws, size_t ws_size,
                              hipStream_t stream)
{
    (void)in_sizes; (void)n_in; (void)out_size; (void)ws_size;
    const float* x      = (const float*)d_in[0];
    const float* ln_g   = (const float*)d_in[1];
    const float* ln_b   = (const float*)d_in[2];
    const float* fc1_w  = (const float*)d_in[3];
    const float* fc1_b  = (const float*)d_in[4];
    const float* fc2_w  = (const float*)d_in[5];
    const float* fc2_b  = (const float*)d_in[6];
    const float* conv1_w= (const float*)d_in[7];
    const float* conv1_b= (const float*)d_in[8];
    const float* conv2_w= (const float*)d_in[9];
    const float* conv2_b= (const float*)d_in[10];
    const float* xl_g   = (const float*)d_in[11];
    const float* xl_b   = (const float*)d_in[12];
    const float* Wg     = (const float*)d_in[13];
    const float* bg     = (const float*)d_in[14];
    const float* Rg     = (const float*)d_in[15];
    const float* gn_g   = (const float*)d_in[16];
    const float* gn_b   = (const float*)d_in[17];
    const float* upl_w  = (const float*)d_in[18];
    const float* upl_b  = (const float*)d_in[19];
    const float* upr_w  = (const float*)d_in[20];
    const float* upr_b  = (const float*)d_in[21];
    const float* down_w = (const float*)d_in[22];
    const float* down_b = (const float*)d_in[23];

    char* ws = (char*)d_ws;
    size_t off = 0;
    auto alloc = [&](size_t bytes) -> char* {
        char* p = ws + off;
        off = (off + bytes + 255) & ~(size_t)255;
        return p;
    };
    float* xn            = (float*)alloc(25165824);          // 6144x1024 f32
    unsigned short* xcb  = (unsigned short*)alloc(12582912); // 6144x1024 bf16
    unsigned short* x1b  = (unsigned short*)alloc(12582912);
    unsigned short* xn2b = (unsigned short*)alloc(12582912);
    unsigned short* gxb  = (unsigned short*)alloc(50331648); // 6144x4096 bf16
    unsigned short* hnb  = (unsigned short*)alloc(12582912);
    unsigned short* glrb = (unsigned short*)alloc(12582912); // 6144x1024 bf16
    unsigned short* yb   = (unsigned short*)alloc(12582912); // 6144x1024 bf16
    unsigned short* WgT  = (unsigned short*)alloc(8388608);  // 4096x1024 bf16
    unsigned short* WupT = (unsigned short*)alloc(4194304);  // 2048x1024 bf16 (interleaved)
    unsigned short* WdT  = (unsigned short*)alloc(2097152);  // 1024x1024 bf16
    float* bup           = (float*)alloc(8192);              // 2048 f32 (interleaved)

    // weight prep (merged: Wg + upl + upr + down transposes in one dispatch)
    prep_weights_kernel<<<dim3(224, 32), 256, 0, stream>>>(
        Wg, upl_w, upr_w, down_w, WgT, WupT, WdT);
    bias_ilv_kernel<<<8, 256, 0, stream>>>(upl_b, upr_b, bup);

    // main pipeline
    ln_fc_kernel<<<512, 512, 0, stream>>>(
        x, ln_g, ln_b, xl_g, xl_b, fc1_w, fc1_b, fc2_w, fc2_b,
        xn, xcb, x1b, xn2b);
    gemm_kernel<0><<<dim3(32, 48), 256, 0, stream>>>(
        xn2b, WgT, bg, gxb, 6144, 4096, 1024, nullptr, nullptr, nullptr);
    slstm_rec_kernel<<<dim3(8, 32), 1024, 0, stream>>>(Rg, gxb, gn_g, gn_b, hnb);
    gemm_kernel<3><<<dim3(16, 48), 256, 0, stream>>>(
        hnb, WupT, bup, glrb, 6144, 2048, 1024, nullptr, nullptr, nullptr);
    gemm_kernel<2><<<dim3(8, 48), 256, 0, stream>>>(
        glrb, WdT, down_b, yb, 6144, 1024, 1024, xcb, x1b, xn);
    tail_fused_kernel<<<512, 512, 0, stream>>>(
        yb, xn, conv1_w, conv1_b, conv2_w, conv2_b, ln_g, ln_b, (float*)d_out);
}

// Round 13
// 443.683 us; speedup vs baseline: 1.2127x; 1.2127x over previous
//
#include <hip/hip_runtime.h>
#include <math.h>

// ---------------------------------------------------------------------------
// xLSTM decoder block, MI355X gfx950.
// R21 = R18/R20 source (best measured: 437.7us on a healthy acquire).
// R20 proved cross-acquire machine variance is ~16-23% (byte-identical code
// measured 437.7 then 538.0; tail 100.0 -> 115.7us): remaining safe levers
// are sub-noise, risky rewrites have negative EV at one shot per round.
// Tail dur is the machine-state calibrator: <=103us means healthy machine.
// Pipeline (all flat (b*12+ch)*1024+l layout):
//  prep:   merged Wg/upl/upr/down bf16 transposes (WupT 16-col interleaved).
//  ln_fc:  FUSED ln1 + fc1(conv k3) + fc2(1x1) + ln2.
//  gemm0:  xn2 @ WgT + bg -> gx (bf16, 6144x4096)
//  rec:    MFMA sLSTM per (head, 16 batches), T14 next-step gx prefetch.
//  gemm3:  hn @ WupT(ilv) -> fused gate epilogue: glr = gelu(l)*r
//  gemm2:  glr @ WdT + down_b ; epilogue y = silu(xc)*(acc+b+x1)+xn -> yb
//  tail:   FUSED conv1+gelu+LN(len)+conv2+skip (R16 2-half structure).
//  GEMM: 2-phase dbuf macro form, linear LDS (swizzle/BM=64 both regressed).
// ---------------------------------------------------------------------------

typedef short short8_t __attribute__((ext_vector_type(8)));
typedef float floatx4 __attribute__((ext_vector_type(4)));
typedef float float2_t __attribute__((ext_vector_type(2)));

typedef unsigned int u32;
typedef const __attribute__((address_space(1))) u32 gu32;
typedef __attribute__((address_space(3))) u32 lu32;

static __device__ __forceinline__ float b2f(unsigned short u) {
    unsigned v = ((unsigned)u) << 16;
    return __builtin_bit_cast(float, v);
}
static __device__ __forceinline__ unsigned short f2b(float f) {
    unsigned u = __builtin_bit_cast(unsigned, f);
    u += 0x7FFFu + ((u >> 16) & 1u);   // RNE
    return (unsigned short)(u >> 16);
}
static __device__ __forceinline__ float2_t make2u(unsigned u) {
    float2_t r;
    r.x = __builtin_bit_cast(float, u << 16);
    r.y = __builtin_bit_cast(float, u & 0xFFFF0000u);
    return r;
}
static __device__ __forceinline__ u32 pack2(float a, float b) {
    return ((u32)f2b(b) << 16) | (u32)f2b(a);
}
// tanh-form gelu in sigmoid shape: x*sigma(2u) == 0.5x(1+tanh(u)).
static __device__ __forceinline__ float gelu_fast(float x) {
    float u = 0.7978845608f * x * (1.f + 0.044715f * x * x);
    u = fminf(fmaxf(u, -9.f), 9.f);
    return x * __builtin_amdgcn_rcpf(1.f + __expf(-2.f * u));
}

// --------------------------- weight prep (merged) --------------------------
// One dispatch, 4 jobs selected by blockIdx.x range. All jobs have K=1024
// (grid.y = 32). dst row = (n>>4)*GS + GO + (n&15).
//   job0: bx [  0,128) Wg   -> WgT  N=4096 GS=16 GO=0
//   job1: bx [128,160) upl  -> WupT N=1024 GS=32 GO=0
//   job2: bx [160,192) upr  -> WupT N=1024 GS=32 GO=16
//   job3: bx [192,224) down -> WdT  N=1024 GS=16 GO=0

__global__ __launch_bounds__(256) void prep_weights_kernel(
    const float* __restrict__ Wg, const float* __restrict__ upl,
    const float* __restrict__ upr, const float* __restrict__ down,
    unsigned short* __restrict__ WgT, unsigned short* __restrict__ WupT,
    unsigned short* __restrict__ WdT)
{
    __shared__ unsigned short tl[32][33];
    const int bx = blockIdx.x;
    const float* src;
    unsigned short* dst;
    int N, GS, GO, n0;
    if (bx < 128)      { src = Wg;   dst = WgT;  N = 4096; GS = 16; GO = 0;  n0 = bx * 32; }
    else if (bx < 160) { src = upl;  dst = WupT; N = 1024; GS = 32; GO = 0;  n0 = (bx - 128) * 32; }
    else if (bx < 192) { src = upr;  dst = WupT; N = 1024; GS = 32; GO = 16; n0 = (bx - 160) * 32; }
    else               { src = down; dst = WdT;  N = 1024; GS = 16; GO = 0;  n0 = (bx - 192) * 32; }
    const int K = 1024;
    const int k0 = blockIdx.y * 32;
    const int tx = threadIdx.x & 31, ty = threadIdx.x >> 5;
#pragma unroll
    for (int r = 0; r < 4; r++) {
        int k = ty + r * 8;
        tl[tx][k] = f2b(src[(size_t)(k0 + k) * N + n0 + tx]);
    }
    __syncthreads();
#pragma unroll
    for (int r = 0; r < 4; r++) {
        int n = n0 + ty * 4 + r;
        size_t row = (size_t)((n >> 4) * GS + GO + (n & 15));
        dst[row * K + k0 + tx] = tl[ty * 4 + r][tx];
    }
}

__global__ __launch_bounds__(256) void bias_ilv_kernel(
    const float* __restrict__ bl, const float* __restrict__ br,
    float* __restrict__ o)
{   // o[2048] interleaved to match WupT rows
    int i = blockIdx.x * 256 + threadIdx.x;
    int grp = i >> 5, w = i & 31;
    o[i] = (w < 16) ? bl[grp * 16 + w] : br[grp * 16 + (w - 16)];
}

// ---- FUSED ln1 + fc1 (conv k3) + fc2 (1x1) + ln2 --------------------------

__global__ __launch_bounds__(512, 2) void ln_fc_kernel(
    const float* __restrict__ x,
    const float* __restrict__ g, const float* __restrict__ be,
    const float* __restrict__ xlg, const float* __restrict__ xlb,
    const float* __restrict__ w1, const float* __restrict__ b1,
    const float* __restrict__ w2, const float* __restrict__ b2,
    float* __restrict__ xn, unsigned short* __restrict__ xcb,
    unsigned short* __restrict__ x1b, unsigned short* __restrict__ xn2b)
{
    __shared__ float sX[12][1028];   // 49.3 KB
    __shared__ float sMR[12][2];
    const int b = blockIdx.x;
    const int t = threadIdx.x;
    const int p = t;                 // positions p, p+512
    const size_t boff = (size_t)b * 12288;

    if (t < 12) { sX[t][0] = 0.f; sX[t][1025] = 0.f; sX[t][1026] = 0.f; sX[t][1027] = 0.f; }
    {
        const float* gx = x + boff;
#pragma unroll
        for (int ci = 0; ci < 12; ci++) {
            sX[ci][1 + p] = gx[ci * 1024 + p];
            sX[ci][1 + p + 512] = gx[ci * 1024 + p + 512];
        }
    }
    __syncthreads();

    // ---- LN1 stats: wave wv handles ch wv, and ch 8+wv for wv<4
    {
        const int wv = t >> 6, la = t & 63;
#pragma unroll
        for (int j = 0; j < 2; j++) {
            const int ch = wv + j * 8;
            if (ch < 12) {
                float s = 0.f, ss = 0.f;
#pragma unroll
                for (int u = 0; u < 16; u++) {
                    float v = sX[ch][1 + la + u * 64];
                    s += v; ss += v * v;
                }
#pragma unroll
                for (int off = 32; off >= 1; off >>= 1) {
                    s += __shfl_xor(s, off);
                    ss += __shfl_xor(ss, off);
                }
                if (la == 0) {
                    float mu = s * (1.f / 1024.f);
                    float var = ss * (1.f / 1024.f) - mu * mu;
                    sMR[ch][0] = mu;
                    sMR[ch][1] = rsqrtf(var + 1e-5f);
                }
            }
        }
    }
    __syncthreads();

    // ---- normalize in place + write xn (skip)
    const float gA = g[p], bA = be[p];
    const float gB = g[p + 512], bB = be[p + 512];
#pragma unroll
    for (int ch = 0; ch < 12; ch++) {
        const float mu = sMR[ch][0], rs = sMR[ch][1];
        float v0 = (sX[ch][1 + p] - mu) * rs * gA + bA;
        float v1 = (sX[ch][1 + p + 512] - mu) * rs * gB + bB;
        sX[ch][1 + p] = v0;
        sX[ch][1 + p + 512] = v1;
        xn[boff + (size_t)ch * 1024 + p] = v0;
        xn[boff + (size_t)ch * 1024 + p + 512] = v1;
    }
    __syncthreads();

    // ---- conv1 (k=3): ci-outer, packed pairs
    float2_t a1[12];
#pragma unroll
    for (int o = 0; o < 12; o++) { float bv = b1[o]; a1[o] = float2_t{bv, bv}; }
    for (int ci = 0; ci < 12; ci++) {
        float2_t vm = float2_t{sX[ci][p],     sX[ci][p + 512]};
        float2_t v0 = float2_t{sX[ci][p + 1], sX[ci][p + 513]};
        float2_t vp = float2_t{sX[ci][p + 2], sX[ci][p + 514]};
        const float* wp = w1 + ci * 3;               // uniform -> SGPR
#pragma unroll
        for (int o = 0; o < 12; o++) {
            const float* wo = wp + o * 36;
            a1[o] += vm * wo[0] + v0 * wo[1] + vp * wo[2];
        }
    }
    __syncthreads();   // all tap reads of sX complete before reuse

#pragma unroll
    for (int o = 0; o < 12; o++) {
        xcb[boff + (size_t)o * 1024 + p] = f2b(a1[o].x);
        xcb[boff + (size_t)o * 1024 + p + 512] = f2b(a1[o].y);
    }

    // ---- fc2 (1x1); stash x1 into sX for LN2 stats
    float2_t a2[12];
#pragma unroll
    for (int o = 0; o < 12; o++) { float bv = b2[o]; a2[o] = float2_t{bv, bv}; }
#pragma unroll
    for (int ci = 0; ci < 12; ci++) {
#pragma unroll
        for (int o = 0; o < 12; o++)
            a2[o] += a1[ci] * w2[o * 12 + ci];
    }
#pragma unroll
    for (int o = 0; o < 12; o++) {
        x1b[boff + (size_t)o * 1024 + p] = f2b(a2[o].x);
        x1b[boff + (size_t)o * 1024 + p + 512] = f2b(a2[o].y);
        sX[o][p] = a2[o].x;
        sX[o][p + 512] = a2[o].y;
    }
    __syncthreads();

    // ---- LN2 stats (plain columns 0..1023)
    {
        const int wv = t >> 6, la = t & 63;
#pragma unroll
        for (int j = 0; j < 2; j++) {
            const int ch = wv + j * 8;
            if (ch < 12) {
                float s = 0.f, ss = 0.f;
#pragma unroll
                for (int u = 0; u < 16; u++) {
                    float v = sX[ch][la + u * 64];
                    s += v; ss += v * v;
                }
#pragma unroll
                for (int off = 32; off >= 1; off >>= 1) {
                    s += __shfl_xor(s, off);
                    ss += __shfl_xor(ss, off);
                }
                if (la == 0) {
                    float mu = s * (1.f / 1024.f);
                    float var = ss * (1.f / 1024.f) - mu * mu;
                    sMR[ch][0] = mu;
                    sMR[ch][1] = rsqrtf(var + 1e-5f);
                }
            }
        }
    }
    __syncthreads();

    // ---- LN2 normalize from registers -> xn2b bf16
    const float xgA = xlg[p], xbA = xlb[p];
    const float xgB = xlg[p + 512], xbB = xlb[p + 512];
#pragma unroll
    for (int ch = 0; ch < 12; ch++) {
        const float mu = sMR[ch][0], rs = sMR[ch][1];
        xn2b[boff + (size_t)ch * 1024 + p] =
            f2b((a2[ch].x - mu) * rs * xgA + xbA);
        xn2b[boff + (size_t)ch * 1024 + p + 512] =
            f2b((a2[ch].y - mu) * rs * xgB + xbB);
    }
}

// ------------------------------ bf16 GEMM ----------------------------------
// MODE 0: store bf16.
// MODE 2: y = silu(xc)*(acc+bias+x1) + skip, store bf16 (xc/x1 bf16).
// MODE 3: fused up-gate: B is 16-col interleaved [l|r]; out (N/2 cols) =
//         gelu(l + bias_l) * (r + bias_r), store bf16.
// 2-phase double-buffered K-loop (linear LDS).

template <int MODE>
__global__ __launch_bounds__(256) void gemm_kernel(
    const unsigned short* __restrict__ A, const unsigned short* __restrict__ BT,
    const float* __restrict__ bias, void* __restrict__ out,
    int M, int N, int K,
    const unsigned short* __restrict__ xcb, const unsigned short* __restrict__ x1b,
    const float* __restrict__ skip)
{
    __shared__ __align__(16) unsigned short sA[2][128 * 32];  // 8 KB x2
    __shared__ __align__(16) unsigned short sB[2][128 * 32];
    const int t = threadIdx.x;
    const int m0 = blockIdx.y * 128;
    const int n0 = blockIdx.x * 128;
    const int w = t >> 6;
    const int lane = t & 63;
    const int wr = (w >> 1) * 64;
    const int wc = (w & 1) * 64;
    const int lrow = lane & 15;
    const int quad = lane >> 4;
    const int row_l = t >> 2;
    const int cs = (t & 3) * 8;

    const unsigned short* gA0 = A + (size_t)(m0 + row_l) * K + cs;
    const unsigned short* gA1 = A + (size_t)(m0 + row_l + 64) * K + cs;
    const unsigned short* gB0 = BT + (size_t)(n0 + row_l) * K + cs;
    const unsigned short* gB1 = BT + (size_t)(n0 + row_l + 64) * K + cs;

    floatx4 acc[4][4];
#pragma unroll
    for (int i = 0; i < 4; i++)
#pragma unroll
        for (int j = 0; j < 4; j++) acc[i][j] = (floatx4)0.f;

#define GEMM_STAGE(buf, k0)                                                        \
    do {                                                                           \
        __builtin_amdgcn_global_load_lds((gu32*)(gA0 + (k0)),                      \
            (lu32*)(&sA[buf][w * 512]), 16, 0, 0);                                 \
        __builtin_amdgcn_global_load_lds((gu32*)(gA1 + (k0)),                      \
            (lu32*)(&sA[buf][2048 + w * 512]), 16, 0, 0);                          \
        __builtin_amdgcn_global_load_lds((gu32*)(gB0 + (k0)),                      \
            (lu32*)(&sB[buf][w * 512]), 16, 0, 0);                                 \
        __builtin_amdgcn_global_load_lds((gu32*)(gB1 + (k0)),                      \
            (lu32*)(&sB[buf][2048 + w * 512]), 16, 0, 0);                          \
    } while (0)

#define GEMM_COMPUTE(buf)                                                          \
    do {                                                                           \
        short8_t af[4], bfr[4];                                                    \
        _Pragma("unroll")                                                          \
        for (int i = 0; i < 4; i++) {                                              \
            af[i] = *(const short8_t*)(&sA[buf][(wr + i * 16 + lrow) * 32 + quad * 8]); \
            bfr[i] = *(const short8_t*)(&sB[buf][(wc + i * 16 + lrow) * 32 + quad * 8]); \
        }                                                                          \
        _Pragma("unroll")                                                          \
        for (int i = 0; i < 4; i++)                                                \
            _Pragma("unroll")                                                      \
            for (int j = 0; j < 4; j++)                                            \
                acc[i][j] = __builtin_amdgcn_mfma_f32_16x16x32_bf16(               \
                    af[i], bfr[j], acc[i][j], 0, 0, 0);                            \
    } while (0)

    GEMM_STAGE(0, 0);
    __syncthreads();
    int cur = 0;
    for (int k0 = 32; k0 < K; k0 += 32) {
        GEMM_STAGE(cur ^ 1, k0);   // issue next tile
        GEMM_COMPUTE(cur);         // compute current
        __syncthreads();           // drains vmcnt; protects buffer reuse
        cur ^= 1;
    }
    GEMM_COMPUTE(cur);             // last tile

#undef GEMM_STAGE
#undef GEMM_COMPUTE

    if (MODE == 3) {
#pragma unroll
        for (int i = 0; i < 4; i++) {
#pragma unroll
            for (int k = 0; k < 2; k++) {
#pragma unroll
                for (int r = 0; r < 4; r++) {
                    const int gm = m0 + wr + i * 16 + quad * 4 + r;
                    const int pl = n0 + wc + k * 32 + lrow;   // physical l col
                    float lv = acc[i][2 * k][r] + bias[pl];
                    float rv = acc[i][2 * k + 1][r] + bias[pl + 16];
                    const int nlog = (pl >> 5) * 16 + lrow;
                    ((unsigned short*)out)[(size_t)gm * (N >> 1) + nlog] =
                        f2b(gelu_fast(lv) * rv);
                }
            }
        }
    } else {
#pragma unroll
        for (int i = 0; i < 4; i++) {
#pragma unroll
            for (int j = 0; j < 4; j++) {
#pragma unroll
                for (int r = 0; r < 4; r++) {
                    const int gm = m0 + wr + i * 16 + quad * 4 + r;
                    const int gn = n0 + wc + j * 16 + lrow;
                    const size_t idx = (size_t)gm * N + gn;
                    float v = acc[i][j][r] + bias[gn];
                    if (MODE == 0) {
                        ((unsigned short*)out)[idx] = f2b(v);
                    } else {
                        float xcv = b2f(xcb[idx]);
                        float sig = xcv * __builtin_amdgcn_rcpf(1.f + __expf(-xcv));
                        ((unsigned short*)out)[idx] =
                            f2b(sig * (v + b2f(x1b[idx])) + skip[idx]);
                    }
                }
            }
        }
    }
}

// ------------------- sLSTM recurrence + GroupNorm (MFMA) -------------------
// grid (NH=8, B/16=32) = 256 blocks (1/CU), block 1024 (16 waves, 4/SIMD).
// T14 prefetch: next step's gx loads issued right after the MFMA.

#define RECP 516   // f32 row stride for sRec (2-way bank aliasing only)
#define HBP  136   // bf16 row stride for sHb

__global__ __launch_bounds__(1024, 1) void slstm_rec_kernel(
    const float* __restrict__ Rg,             // [8][512][128] f32
    const unsigned short* __restrict__ gxb,   // [B][12][4096] bf16
    const float* __restrict__ gn_g, const float* __restrict__ gn_b,
    unsigned short* __restrict__ hnb)         // [B][12][1024] bf16
{
    __shared__ __align__(16) float sRec[16 * RECP];
    __shared__ __align__(16) unsigned short sHb[16 * HBP];
    const int head = blockIdx.x;
    const int b0 = blockIdx.y * 16;
    const int t = threadIdx.x;
    const int w = t >> 6;
    const int lane = t & 63;
    const int quad = lane >> 4;
    const int l16 = lane & 15;

    short8_t Bf[2][4];
    {
        const float* Rh = Rg + (size_t)head * 65536;
#pragma unroll
        for (int jt = 0; jt < 2; jt++)
#pragma unroll
            for (int kk = 0; kk < 4; kk++) {
                const float* src =
                    Rh + (size_t)(w * 32 + jt * 16 + l16) * 128 + kk * 32 + quad * 8;
                short8_t v;
#pragma unroll
                for (int j = 0; j < 8; j++) v[j] = (short)f2b(src[j]);
                Bf[jt][kk] = v;
            }
    }

    for (int i = t; i < 16 * HBP; i += 1024) sHb[i] = 0;

    const int la = lane;
    float c0 = 0.f, n0s = 0.f, m0 = 0.f;
    float c1 = 0.f, n1s = 0.f, m1 = 0.f;
    const float gg0 = gn_g[head * 128 + la];
    const float gg1 = gn_g[head * 128 + la + 64];
    const float gb0 = gn_b[head * 128 + la];
    const float gb1 = gn_b[head * 128 + la + 64];

    const unsigned short* gbase = gxb + (size_t)(b0 + w) * 12 * 4096 + head * 512;
    float gv[8];
#pragma unroll
    for (int q = 0; q < 8; q++) gv[q] = b2f(gbase[q * 64 + la]);   // step 0

    __syncthreads();

    for (int step = 0; step < 12; step++) {
        float gz0 = gv[0], gz1 = gv[1];
        float gi0 = gv[2], gi1 = gv[3];
        float gf0 = gv[4], gf1 = gv[5];
        float go0 = gv[6], go1 = gv[7];

        short8_t Af[4];
#pragma unroll
        for (int kk = 0; kk < 4; kk++)
            Af[kk] = *(const short8_t*)(sHb + l16 * HBP + kk * 32 + quad * 8);
        floatx4 D0 = (floatx4)0.f, D1 = (floatx4)0.f;
#pragma unroll
        for (int kk = 0; kk < 4; kk++) {
            D0 = __builtin_amdgcn_mfma_f32_16x16x32_bf16(Af[kk], Bf[0][kk], D0, 0, 0, 0);
            D1 = __builtin_amdgcn_mfma_f32_16x16x32_bf16(Af[kk], Bf[1][kk], D1, 0, 0, 0);
        }

        // ---- prefetch next step's gx (clamped index; unused at step 11).
        {
            const int sn = (step < 11) ? step + 1 : step;
            const unsigned short* gpn = gbase + (size_t)sn * 4096;
#pragma unroll
            for (int q = 0; q < 8; q++) gv[q] = b2f(gpn[q * 64 + la]);
        }

#pragma unroll
        for (int r = 0; r < 4; r++) {
            sRec[(quad * 4 + r) * RECP + w * 32 + l16] = D0[r];
            sRec[(quad * 4 + r) * RECP + w * 32 + 16 + l16] = D1[r];
        }
        __syncthreads();

        const float* rr = sRec + w * RECP;
        float zp0 = gz0 + rr[la],       zp1 = gz1 + rr[64 + la];
        float ip0 = gi0 + rr[128 + la], ip1 = gi1 + rr[192 + la];
        float fp0 = gf0 + rr[256 + la], fp1 = gf1 + rr[320 + la];
        float op0 = go0 + rr[384 + la], op1 = go1 + rr[448 + la];

        // tanh via sigmoid form + v_rcp (graceful at +/-inf preacts)
        float e20 = __expf(-2.f * zp0), e21 = __expf(-2.f * zp1);
        float z0 = 2.f * __builtin_amdgcn_rcpf(1.f + e20) - 1.f;
        float z1 = 2.f * __builtin_amdgcn_rcpf(1.f + e21) - 1.f;
        float o0 = __builtin_amdgcn_rcpf(1.f + __expf(-op0));
        float o1 = __builtin_amdgcn_rcpf(1.f + __expf(-op1));
        float mn0 = fmaxf(fp0 + m0, ip0), mn1 = fmaxf(fp1 + m1, ip1);
        float ie0 = __expf(ip0 - mn0), ie1 = __expf(ip1 - mn1);
        float fe0 = __expf(fp0 + m0 - mn0), fe1 = __expf(fp1 + m1 - mn1);
        c0 = fe0 * c0 + ie0 * z0;  c1 = fe1 * c1 + ie1 * z1;
        n0s = fe0 * n0s + ie0;     n1s = fe1 * n1s + ie1;
        m0 = mn0;                  m1 = mn1;
        float h0 = o0 * c0 * __builtin_amdgcn_rcpf(n0s);
        float h1 = o1 * c1 * __builtin_amdgcn_rcpf(n1s);

        float s = h0 + h1, ss = h0 * h0 + h1 * h1;
#pragma unroll
        for (int off = 32; off >= 1; off >>= 1) {
            s += __shfl_xor(s, off);
            ss += __shfl_xor(ss, off);
        }
        float mu = s * (1.f / 128.f);
        float var = ss * (1.f / 128.f) - mu * mu;
        float rs = rsqrtf(var + 1e-5f);
        size_t base = ((size_t)(b0 + w) * 12 + step) * 1024 + head * 128;
        hnb[base + la] = f2b((h0 - mu) * rs * gg0 + gb0);
        hnb[base + la + 64] = f2b((h1 - mu) * rs * gg1 + gb1);

        sHb[w * HBP + la] = f2b(h0);
        sHb[w * HBP + la + 64] = f2b(h1);
        __syncthreads();
    }
}

// ---------------- fused tail: conv1+gelu+LN(len)+conv2+skip ----------------
// R16 2-half structure (measured ~100us on healthy acquire, VGPR 56).

__global__ __launch_bounds__(512, 2) void tail_fused_kernel(
    const unsigned short* __restrict__ y, const float* __restrict__ skip,
    const float* __restrict__ w1, const float* __restrict__ b1,
    const float* __restrict__ w2, const float* __restrict__ b2,
    const float* __restrict__ lng, const float* __restrict__ lnb,
    float* __restrict__ out)
{
    __shared__ unsigned short sY[12][1026];   // 24.6 KB
    __shared__ unsigned short sZ[24][1026];   // 49.2 KB
    __shared__ float sMR[24][2];
    const int b = blockIdx.x;
    const int t = threadIdx.x;
    const int p = t;                          // positions p, p+512
    const size_t boff = (size_t)b * 12288;

    {
        const u32* gy = (const u32*)(y + boff);
#pragma unroll
        for (int ci = 0; ci < 12; ci++)
            ((u32*)&sY[ci][0])[t] = gy[ci * 512 + t];
    }
    // LN gains for the dword-mapped normalize pass (positions 2t, 2t+1)
    const float lgA = lng[2 * t], lbA = lnb[2 * t];
    const float lgB = lng[2 * t + 1], lbB = lnb[2 * t + 1];
    __syncthreads();

    float2_t acc[12];
#pragma unroll
    for (int o = 0; o < 12; o++) { float bv = b2[o]; acc[o] = float2_t{bv, bv}; }

    for (int h = 0; h < 2; h++) {
        // ---- conv1: 12 in -> this half's 24 out channels, ci-outer
        float2_t a1[24];
#pragma unroll
        for (int o = 0; o < 24; o++) {
            float bo = b1[h * 24 + o];
            a1[o] = float2_t{bo, bo};
        }
        for (int ci = 0; ci < 12; ci++) {
            float2_t v0 = float2_t{b2f(sY[ci][p]), b2f(sY[ci][p + 512])};
            float2_t vm = float2_t{(p > 0) ? b2f(sY[ci][p - 1]) : 0.f,
                                   b2f(sY[ci][p + 511])};
            float2_t vp = float2_t{b2f(sY[ci][p + 1]),
                                   (p < 511) ? b2f(sY[ci][p + 513]) : 0.f};
            const float* wp = w1 + ci * 3;             // uniform -> SGPR
#pragma unroll
            for (int o = 0; o < 24; o++) {
                const float* wo = wp + (h * 24 + o) * 36;
                a1[o] += vm * wo[0] + v0 * wo[1] + vp * wo[2];
            }
        }
#pragma unroll
        for (int o = 0; o < 24; o++) {
            sZ[o][p] = f2b(gelu_fast(a1[o].x));
            sZ[o][p + 512] = f2b(gelu_fast(a1[o].y));
        }
        __syncthreads();

        // ---- LN stats: wave wv handles ch wv, wv+8, wv+16
        {
            const int wv = t >> 6, la = t & 63;
#pragma unroll
            for (int j = 0; j < 3; j++) {
                const int ch = wv + j * 8;
                float s = 0.f, ss = 0.f;
#pragma unroll
                for (int u = 0; u < 8; u++) {
                    float2_t v = make2u(((const u32*)&sZ[ch][0])[la + u * 64]);
                    s += v.x + v.y;
                    ss += v.x * v.x + v.y * v.y;
                }
#pragma unroll
                for (int off = 32; off >= 1; off >>= 1) {
                    s += __shfl_xor(s, off);
                    ss += __shfl_xor(ss, off);
                }
                if (la == 0) {
                    float mu = s * (1.f / 1024.f);
                    float var = ss * (1.f / 1024.f) - mu * mu;
                    sMR[ch][0] = mu;
                    sMR[ch][1] = rsqrtf(var + 1e-5f);
                }
            }
        }
        __syncthreads();

        // ---- normalize in place (dword mapping: one b32 read+write per ch)
#pragma unroll
        for (int ch = 0; ch < 24; ch++) {
            const float mu = sMR[ch][0], rs = sMR[ch][1];
            float2_t f = make2u(((const u32*)&sZ[ch][0])[t]);
            f.x = (f.x - mu) * rs * lgA + lbA;
            f.y = (f.y - mu) * rs * lgB + lbB;
            ((u32*)&sZ[ch][0])[t] = pack2(f.x, f.y);
        }
        __syncthreads();

        // ---- conv2 partial over this half's 24 input channels
        for (int ci = 0; ci < 24; ci++) {
            float2_t z0 = float2_t{b2f(sZ[ci][p]), b2f(sZ[ci][p + 512])};
            float2_t zm = float2_t{(p > 0) ? b2f(sZ[ci][p - 1]) : 0.f,
                                   b2f(sZ[ci][p + 511])};
            float2_t zp = float2_t{b2f(sZ[ci][p + 1]),
                                   (p < 511) ? b2f(sZ[ci][p + 513]) : 0.f};
            const float* wp = w2 + (h * 24 + ci) * 3;  // uniform -> SGPR
#pragma unroll
            for (int o = 0; o < 12; o++)
                acc[o] += zm * wp[o * 144] + z0 * wp[o * 144 + 1]
                        + zp * wp[o * 144 + 2];
        }
        __syncthreads();   // before next half overwrites sZ
    }

#pragma unroll
    for (int o = 0; o < 12; o++) {
        size_t i0 = boff + (size_t)o * 1024 + p;
        out[i0] = acc[o].x + skip[i0];
        out[i0 + 512] = acc[o].y + skip[i0 + 512];
    }
}

// ------------------------------ launcher -----------------------------------

extern "C" void kernel_launch(void* const* d_in, const int* in_sizes, int n_in,
                              void* d_out, int out_size, void* d_ws, size_t ws_size,
                              hipStream_t stream)
{
    (void)in_sizes; (void)n_in; (void)out_size; (void)ws_size;
    const float* x      = (const float*)d_in[0];
    const float* ln_g   = (const float*)d_in[1];
    const float* ln_b   = (const float*)d_in[2];
    const float* fc1_w  = (const float*)d_in[3];
    const float* fc1_b  = (const float*)d_in[4];
    const float* fc2_w  = (const float*)d_in[5];
    const float* fc2_b  = (const float*)d_in[6];
    const float* conv1_w= (const float*)d_in[7];
    const float* conv1_b= (const float*)d_in[8];
    const float* conv2_w= (const float*)d_in[9];
    const float* conv2_b= (const float*)d_in[10];
    const float* xl_g   = (const float*)d_in[11];
    const float* xl_b   = (const float*)d_in[12];
    const float* Wg     = (const float*)d_in[13];
    const float* bg     = (const float*)d_in[14];
    const float* Rg     = (const float*)d_in[15];
    const float* gn_g   = (const float*)d_in[16];
    const float* gn_b   = (const float*)d_in[17];
    const float* upl_w  = (const float*)d_in[18];
    const float* upl_b  = (const float*)d_in[19];
    const float* upr_w  = (const float*)d_in[20];
    const float* upr_b  = (const float*)d_in[21];
    const float* down_w = (const float*)d_in[22];
    const float* down_b = (const float*)d_in[23];

    char* ws = (char*)d_ws;
    size_t off = 0;
    auto alloc = [&](size_t bytes) -> char* {
        char* p = ws + off;
        off = (off + bytes + 255) & ~(size_t)255;
        return p;
    };
    float* xn            = (float*)alloc(25165824);          // 6144x1024 f32
    unsigned short* xcb  = (unsigned short*)alloc(12582912); // 6144x1024 bf16
    unsigned short* x1b  = (unsigned short*)alloc(12582912);
    unsigned short* xn2b = (unsigned short*)alloc(12582912);
    unsigned short* gxb  = (unsigned short*)alloc(50331648); // 6144x4096 bf16
    unsigned short* hnb  = (unsigned short*)alloc(12582912);
    unsigned short* glrb = (unsigned short*)alloc(12582912); // 6144x1024 bf16
    unsigned short* yb   = (unsigned short*)alloc(12582912); // 6144x1024 bf16
    unsigned short* WgT  = (unsigned short*)alloc(8388608);  // 4096x1024 bf16
    unsigned short* WupT = (unsigned short*)alloc(4194304);  // 2048x1024 bf16 (interleaved)
    unsigned short* WdT  = (unsigned short*)alloc(2097152);  // 1024x1024 bf16
    float* bup           = (float*)alloc(8192);              // 2048 f32 (interleaved)

    // weight prep (merged: Wg + upl + upr + down transposes in one dispatch)
    prep_weights_kernel<<<dim3(224, 32), 256, 0, stream>>>(
        Wg, upl_w, upr_w, down_w, WgT, WupT, WdT);
    bias_ilv_kernel<<<8, 256, 0, stream>>>(upl_b, upr_b, bup);

    // main pipeline
    ln_fc_kernel<<<512, 512, 0, stream>>>(
        x, ln_g, ln_b, xl_g, xl_b, fc1_w, fc1_b, fc2_w, fc2_b,
        xn, xcb, x1b, xn2b);
    gemm_kernel<0><<<dim3(32, 48), 256, 0, stream>>>(
        xn2b, WgT, bg, gxb, 6144, 4096, 1024, nullptr, nullptr, nullptr);
    slstm_rec_kernel<<<dim3(8, 32), 1024, 0, stream>>>(Rg, gxb, gn_g, gn_b, hnb);
    gemm_kernel<3><<<dim3(16, 48), 256, 0, stream>>>(
        hnb, WupT, bup, glrb, 6144, 2048, 1024, nullptr, nullptr, nullptr);
    gemm_kernel<2><<<dim3(8, 48), 256, 0, stream>>>(
        glrb, WdT, down_b, yb, 6144, 1024, 1024, xcb, x1b, xn);
    tail_fused_kernel<<<512, 512, 0, stream>>>(
        yb, xn, conv1_w, conv1_b, conv2_w, conv2_b, ln_g, ln_b, (float*)d_out);
}

// Round 14
// 436.055 us; speedup vs baseline: 1.2339x; 1.0175x over previous
//
#include <hip/hip_runtime.h>
#include <math.h>

// ---------------------------------------------------------------------------
// xLSTM decoder block, MI355X gfx950.
// R22 = confirmed-best R18/R21 source + bias_ilv absorbed into prep (one
// fewer dispatch; this prep variant already passed in R19).
// Cross-acquire noise calibration (byte-identical code): 437.7 / 538.0 /
// 443.7 us. Healthy-machine value ~438-444us; tail dur <=103us = healthy.
// Pipeline (all flat (b*12+ch)*1024+l layout):
//  prep:   merged Wg/upl/upr/down bf16 transposes (WupT 16-col interleaved)
//          + bup bias interleave, one dispatch via job table.
//  ln_fc:  FUSED ln1 + fc1(conv k3) + fc2(1x1) + ln2.
//  gemm0:  xn2 @ WgT + bg -> gx (bf16, 6144x4096)
//  rec:    MFMA sLSTM per (head, 16 batches), T14 next-step gx prefetch.
//  gemm3:  hn @ WupT(ilv) -> fused gate epilogue: glr = gelu(l)*r
//  gemm2:  glr @ WdT + down_b ; epilogue y = silu(xc)*(acc+b+x1)+xn -> yb
//  tail:   FUSED conv1+gelu+LN(len)+conv2+skip (R16 2-half structure).
//  GEMM: 2-phase dbuf macro form, linear LDS (swizzle/BM=64 both regressed).
// ---------------------------------------------------------------------------

typedef short short8_t __attribute__((ext_vector_type(8)));
typedef float floatx4 __attribute__((ext_vector_type(4)));
typedef float float2_t __attribute__((ext_vector_type(2)));

typedef unsigned int u32;
typedef const __attribute__((address_space(1))) u32 gu32;
typedef __attribute__((address_space(3))) u32 lu32;

static __device__ __forceinline__ float b2f(unsigned short u) {
    unsigned v = ((unsigned)u) << 16;
    return __builtin_bit_cast(float, v);
}
static __device__ __forceinline__ unsigned short f2b(float f) {
    unsigned u = __builtin_bit_cast(unsigned, f);
    u += 0x7FFFu + ((u >> 16) & 1u);   // RNE
    return (unsigned short)(u >> 16);
}
static __device__ __forceinline__ float2_t make2u(unsigned u) {
    float2_t r;
    r.x = __builtin_bit_cast(float, u << 16);
    r.y = __builtin_bit_cast(float, u & 0xFFFF0000u);
    return r;
}
static __device__ __forceinline__ u32 pack2(float a, float b) {
    return ((u32)f2b(b) << 16) | (u32)f2b(a);
}
// tanh-form gelu in sigmoid shape: x*sigma(2u) == 0.5x(1+tanh(u)).
static __device__ __forceinline__ float gelu_fast(float x) {
    float u = 0.7978845608f * x * (1.f + 0.044715f * x * x);
    u = fminf(fmaxf(u, -9.f), 9.f);
    return x * __builtin_amdgcn_rcpf(1.f + __expf(-2.f * u));
}

// --------------------------- weight prep (merged) --------------------------
// One dispatch, jobs by blockIdx.x range (K=1024 for all, grid.y=32):
//   bx [  0,128) Wg   -> WgT  N=4096 GS=16 GO=0
//   bx [128,160) upl  -> WupT N=1024 GS=32 GO=0
//   bx [160,192) upr  -> WupT N=1024 GS=32 GO=16
//   bx [192,224) down -> WdT  N=1024 GS=16 GO=0
//   bx [224,232) bup bias interleave (y==0 only)

__global__ __launch_bounds__(256) void prep_weights_kernel(
    const float* __restrict__ Wg, const float* __restrict__ upl,
    const float* __restrict__ upr, const float* __restrict__ down,
    const float* __restrict__ upl_b, const float* __restrict__ upr_b,
    unsigned short* __restrict__ WgT, unsigned short* __restrict__ WupT,
    unsigned short* __restrict__ WdT, float* __restrict__ bup)
{
    __shared__ unsigned short tl[32][33];
    const int bx = blockIdx.x;
    if (bx >= 224) {   // bias interleave job
        if (blockIdx.y != 0) return;
        int i = (bx - 224) * 256 + threadIdx.x;          // 0..2047
        int grp = i >> 5, wv = i & 31;
        bup[i] = (wv < 16) ? upl_b[grp * 16 + wv] : upr_b[grp * 16 + (wv - 16)];
        return;
    }
    const float* src;
    unsigned short* dst;
    int N, GS, GO, n0;
    if (bx < 128)      { src = Wg;   dst = WgT;  N = 4096; GS = 16; GO = 0;  n0 = bx * 32; }
    else if (bx < 160) { src = upl;  dst = WupT; N = 1024; GS = 32; GO = 0;  n0 = (bx - 128) * 32; }
    else if (bx < 192) { src = upr;  dst = WupT; N = 1024; GS = 32; GO = 16; n0 = (bx - 160) * 32; }
    else               { src = down; dst = WdT;  N = 1024; GS = 16; GO = 0;  n0 = (bx - 192) * 32; }
    const int K = 1024;
    const int k0 = blockIdx.y * 32;
    const int tx = threadIdx.x & 31, ty = threadIdx.x >> 5;
#pragma unroll
    for (int r = 0; r < 4; r++) {
        int k = ty + r * 8;
        tl[tx][k] = f2b(src[(size_t)(k0 + k) * N + n0 + tx]);
    }
    __syncthreads();
#pragma unroll
    for (int r = 0; r < 4; r++) {
        int n = n0 + ty * 4 + r;
        size_t row = (size_t)((n >> 4) * GS + GO + (n & 15));
        dst[row * K + k0 + tx] = tl[ty * 4 + r][tx];
    }
}

// ---- FUSED ln1 + fc1 (conv k3) + fc2 (1x1) + ln2 --------------------------

__global__ __launch_bounds__(512, 2) void ln_fc_kernel(
    const float* __restrict__ x,
    const float* __restrict__ g, const float* __restrict__ be,
    const float* __restrict__ xlg, const float* __restrict__ xlb,
    const float* __restrict__ w1, const float* __restrict__ b1,
    const float* __restrict__ w2, const float* __restrict__ b2,
    float* __restrict__ xn, unsigned short* __restrict__ xcb,
    unsigned short* __restrict__ x1b, unsigned short* __restrict__ xn2b)
{
    __shared__ float sX[12][1028];   // 49.3 KB
    __shared__ float sMR[12][2];
    const int b = blockIdx.x;
    const int t = threadIdx.x;
    const int p = t;                 // positions p, p+512
    const size_t boff = (size_t)b * 12288;

    if (t < 12) { sX[t][0] = 0.f; sX[t][1025] = 0.f; sX[t][1026] = 0.f; sX[t][1027] = 0.f; }
    {
        const float* gx = x + boff;
#pragma unroll
        for (int ci = 0; ci < 12; ci++) {
            sX[ci][1 + p] = gx[ci * 1024 + p];
            sX[ci][1 + p + 512] = gx[ci * 1024 + p + 512];
        }
    }
    __syncthreads();

    // ---- LN1 stats: wave wv handles ch wv, and ch 8+wv for wv<4
    {
        const int wv = t >> 6, la = t & 63;
#pragma unroll
        for (int j = 0; j < 2; j++) {
            const int ch = wv + j * 8;
            if (ch < 12) {
                float s = 0.f, ss = 0.f;
#pragma unroll
                for (int u = 0; u < 16; u++) {
                    float v = sX[ch][1 + la + u * 64];
                    s += v; ss += v * v;
                }
#pragma unroll
                for (int off = 32; off >= 1; off >>= 1) {
                    s += __shfl_xor(s, off);
                    ss += __shfl_xor(ss, off);
                }
                if (la == 0) {
                    float mu = s * (1.f / 1024.f);
                    float var = ss * (1.f / 1024.f) - mu * mu;
                    sMR[ch][0] = mu;
                    sMR[ch][1] = rsqrtf(var + 1e-5f);
                }
            }
        }
    }
    __syncthreads();

    // ---- normalize in place + write xn (skip)
    const float gA = g[p], bA = be[p];
    const float gB = g[p + 512], bB = be[p + 512];
#pragma unroll
    for (int ch = 0; ch < 12; ch++) {
        const float mu = sMR[ch][0], rs = sMR[ch][1];
        float v0 = (sX[ch][1 + p] - mu) * rs * gA + bA;
        float v1 = (sX[ch][1 + p + 512] - mu) * rs * gB + bB;
        sX[ch][1 + p] = v0;
        sX[ch][1 + p + 512] = v1;
        xn[boff + (size_t)ch * 1024 + p] = v0;
        xn[boff + (size_t)ch * 1024 + p + 512] = v1;
    }
    __syncthreads();

    // ---- conv1 (k=3): ci-outer, packed pairs
    float2_t a1[12];
#pragma unroll
    for (int o = 0; o < 12; o++) { float bv = b1[o]; a1[o] = float2_t{bv, bv}; }
    for (int ci = 0; ci < 12; ci++) {
        float2_t vm = float2_t{sX[ci][p],     sX[ci][p + 512]};
        float2_t v0 = float2_t{sX[ci][p + 1], sX[ci][p + 513]};
        float2_t vp = float2_t{sX[ci][p + 2], sX[ci][p + 514]};
        const float* wp = w1 + ci * 3;               // uniform -> SGPR
#pragma unroll
        for (int o = 0; o < 12; o++) {
            const float* wo = wp + o * 36;
            a1[o] += vm * wo[0] + v0 * wo[1] + vp * wo[2];
        }
    }
    __syncthreads();   // all tap reads of sX complete before reuse

#pragma unroll
    for (int o = 0; o < 12; o++) {
        xcb[boff + (size_t)o * 1024 + p] = f2b(a1[o].x);
        xcb[boff + (size_t)o * 1024 + p + 512] = f2b(a1[o].y);
    }

    // ---- fc2 (1x1); stash x1 into sX for LN2 stats
    float2_t a2[12];
#pragma unroll
    for (int o = 0; o < 12; o++) { float bv = b2[o]; a2[o] = float2_t{bv, bv}; }
#pragma unroll
    for (int ci = 0; ci < 12; ci++) {
#pragma unroll
        for (int o = 0; o < 12; o++)
            a2[o] += a1[ci] * w2[o * 12 + ci];
    }
#pragma unroll
    for (int o = 0; o < 12; o++) {
        x1b[boff + (size_t)o * 1024 + p] = f2b(a2[o].x);
        x1b[boff + (size_t)o * 1024 + p + 512] = f2b(a2[o].y);
        sX[o][p] = a2[o].x;
        sX[o][p + 512] = a2[o].y;
    }
    __syncthreads();

    // ---- LN2 stats (plain columns 0..1023)
    {
        const int wv = t >> 6, la = t & 63;
#pragma unroll
        for (int j = 0; j < 2; j++) {
            const int ch = wv + j * 8;
            if (ch < 12) {
                float s = 0.f, ss = 0.f;
#pragma unroll
                for (int u = 0; u < 16; u++) {
                    float v = sX[ch][la + u * 64];
                    s += v; ss += v * v;
                }
#pragma unroll
                for (int off = 32; off >= 1; off >>= 1) {
                    s += __shfl_xor(s, off);
                    ss += __shfl_xor(ss, off);
                }
                if (la == 0) {
                    float mu = s * (1.f / 1024.f);
                    float var = ss * (1.f / 1024.f) - mu * mu;
                    sMR[ch][0] = mu;
                    sMR[ch][1] = rsqrtf(var + 1e-5f);
                }
            }
        }
    }
    __syncthreads();

    // ---- LN2 normalize from registers -> xn2b bf16
    const float xgA = xlg[p], xbA = xlb[p];
    const float xgB = xlg[p + 512], xbB = xlb[p + 512];
#pragma unroll
    for (int ch = 0; ch < 12; ch++) {
        const float mu = sMR[ch][0], rs = sMR[ch][1];
        xn2b[boff + (size_t)ch * 1024 + p] =
            f2b((a2[ch].x - mu) * rs * xgA + xbA);
        xn2b[boff + (size_t)ch * 1024 + p + 512] =
            f2b((a2[ch].y - mu) * rs * xgB + xbB);
    }
}

// ------------------------------ bf16 GEMM ----------------------------------
// MODE 0: store bf16.
// MODE 2: y = silu(xc)*(acc+bias+x1) + skip, store bf16 (xc/x1 bf16).
// MODE 3: fused up-gate: B is 16-col interleaved [l|r]; out (N/2 cols) =
//         gelu(l + bias_l) * (r + bias_r), store bf16.
// 2-phase double-buffered K-loop (linear LDS).

template <int MODE>
__global__ __launch_bounds__(256) void gemm_kernel(
    const unsigned short* __restrict__ A, const unsigned short* __restrict__ BT,
    const float* __restrict__ bias, void* __restrict__ out,
    int M, int N, int K,
    const unsigned short* __restrict__ xcb, const unsigned short* __restrict__ x1b,
    const float* __restrict__ skip)
{
    __shared__ __align__(16) unsigned short sA[2][128 * 32];  // 8 KB x2
    __shared__ __align__(16) unsigned short sB[2][128 * 32];
    const int t = threadIdx.x;
    const int m0 = blockIdx.y * 128;
    const int n0 = blockIdx.x * 128;
    const int w = t >> 6;
    const int lane = t & 63;
    const int wr = (w >> 1) * 64;
    const int wc = (w & 1) * 64;
    const int lrow = lane & 15;
    const int quad = lane >> 4;
    const int row_l = t >> 2;
    const int cs = (t & 3) * 8;

    const unsigned short* gA0 = A + (size_t)(m0 + row_l) * K + cs;
    const unsigned short* gA1 = A + (size_t)(m0 + row_l + 64) * K + cs;
    const unsigned short* gB0 = BT + (size_t)(n0 + row_l) * K + cs;
    const unsigned short* gB1 = BT + (size_t)(n0 + row_l + 64) * K + cs;

    floatx4 acc[4][4];
#pragma unroll
    for (int i = 0; i < 4; i++)
#pragma unroll
        for (int j = 0; j < 4; j++) acc[i][j] = (floatx4)0.f;

#define GEMM_STAGE(buf, k0)                                                        \
    do {                                                                           \
        __builtin_amdgcn_global_load_lds((gu32*)(gA0 + (k0)),                      \
            (lu32*)(&sA[buf][w * 512]), 16, 0, 0);                                 \
        __builtin_amdgcn_global_load_lds((gu32*)(gA1 + (k0)),                      \
            (lu32*)(&sA[buf][2048 + w * 512]), 16, 0, 0);                          \
        __builtin_amdgcn_global_load_lds((gu32*)(gB0 + (k0)),                      \
            (lu32*)(&sB[buf][w * 512]), 16, 0, 0);                                 \
        __builtin_amdgcn_global_load_lds((gu32*)(gB1 + (k0)),                      \
            (lu32*)(&sB[buf][2048 + w * 512]), 16, 0, 0);                          \
    } while (0)

#define GEMM_COMPUTE(buf)                                                          \
    do {                                                                           \
        short8_t af[4], bfr[4];                                                    \
        _Pragma("unroll")                                                          \
        for (int i = 0; i < 4; i++) {                                              \
            af[i] = *(const short8_t*)(&sA[buf][(wr + i * 16 + lrow) * 32 + quad * 8]); \
            bfr[i] = *(const short8_t*)(&sB[buf][(wc + i * 16 + lrow) * 32 + quad * 8]); \
        }                                                                          \
        _Pragma("unroll")                                                          \
        for (int i = 0; i < 4; i++)                                                \
            _Pragma("unroll")                                                      \
            for (int j = 0; j < 4; j++)                                            \
                acc[i][j] = __builtin_amdgcn_mfma_f32_16x16x32_bf16(               \
                    af[i], bfr[j], acc[i][j], 0, 0, 0);                            \
    } while (0)

    GEMM_STAGE(0, 0);
    __syncthreads();
    int cur = 0;
    for (int k0 = 32; k0 < K; k0 += 32) {
        GEMM_STAGE(cur ^ 1, k0);   // issue next tile
        GEMM_COMPUTE(cur);         // compute current
        __syncthreads();           // drains vmcnt; protects buffer reuse
        cur ^= 1;
    }
    GEMM_COMPUTE(cur);             // last tile

#undef GEMM_STAGE
#undef GEMM_COMPUTE

    if (MODE == 3) {
#pragma unroll
        for (int i = 0; i < 4; i++) {
#pragma unroll
            for (int k = 0; k < 2; k++) {
#pragma unroll
                for (int r = 0; r < 4; r++) {
                    const int gm = m0 + wr + i * 16 + quad * 4 + r;
                    const int pl = n0 + wc + k * 32 + lrow;   // physical l col
                    float lv = acc[i][2 * k][r] + bias[pl];
                    float rv = acc[i][2 * k + 1][r] + bias[pl + 16];
                    const int nlog = (pl >> 5) * 16 + lrow;
                    ((unsigned short*)out)[(size_t)gm * (N >> 1) + nlog] =
                        f2b(gelu_fast(lv) * rv);
                }
            }
        }
    } else {
#pragma unroll
        for (int i = 0; i < 4; i++) {
#pragma unroll
            for (int j = 0; j < 4; j++) {
#pragma unroll
                for (int r = 0; r < 4; r++) {
                    const int gm = m0 + wr + i * 16 + quad * 4 + r;
                    const int gn = n0 + wc + j * 16 + lrow;
                    const size_t idx = (size_t)gm * N + gn;
                    float v = acc[i][j][r] + bias[gn];
                    if (MODE == 0) {
                        ((unsigned short*)out)[idx] = f2b(v);
                    } else {
                        float xcv = b2f(xcb[idx]);
                        float sig = xcv * __builtin_amdgcn_rcpf(1.f + __expf(-xcv));
                        ((unsigned short*)out)[idx] =
                            f2b(sig * (v + b2f(x1b[idx])) + skip[idx]);
                    }
                }
            }
        }
    }
}

// ------------------- sLSTM recurrence + GroupNorm (MFMA) -------------------
// grid (NH=8, B/16=32) = 256 blocks (1/CU), block 1024 (16 waves, 4/SIMD).
// T14 prefetch: next step's gx loads issued right after the MFMA.

#define RECP 516   // f32 row stride for sRec (2-way bank aliasing only)
#define HBP  136   // bf16 row stride for sHb

__global__ __launch_bounds__(1024, 1) void slstm_rec_kernel(
    const float* __restrict__ Rg,             // [8][512][128] f32
    const unsigned short* __restrict__ gxb,   // [B][12][4096] bf16
    const float* __restrict__ gn_g, const float* __restrict__ gn_b,
    unsigned short* __restrict__ hnb)         // [B][12][1024] bf16
{
    __shared__ __align__(16) float sRec[16 * RECP];
    __shared__ __align__(16) unsigned short sHb[16 * HBP];
    const int head = blockIdx.x;
    const int b0 = blockIdx.y * 16;
    const int t = threadIdx.x;
    const int w = t >> 6;
    const int lane = t & 63;
    const int quad = lane >> 4;
    const int l16 = lane & 15;

    short8_t Bf[2][4];
    {
        const float* Rh = Rg + (size_t)head * 65536;
#pragma unroll
        for (int jt = 0; jt < 2; jt++)
#pragma unroll
            for (int kk = 0; kk < 4; kk++) {
                const float* src =
                    Rh + (size_t)(w * 32 + jt * 16 + l16) * 128 + kk * 32 + quad * 8;
                short8_t v;
#pragma unroll
                for (int j = 0; j < 8; j++) v[j] = (short)f2b(src[j]);
                Bf[jt][kk] = v;
            }
    }

    for (int i = t; i < 16 * HBP; i += 1024) sHb[i] = 0;

    const int la = lane;
    float c0 = 0.f, n0s = 0.f, m0 = 0.f;
    float c1 = 0.f, n1s = 0.f, m1 = 0.f;
    const float gg0 = gn_g[head * 128 + la];
    const float gg1 = gn_g[head * 128 + la + 64];
    const float gb0 = gn_b[head * 128 + la];
    const float gb1 = gn_b[head * 128 + la + 64];

    const unsigned short* gbase = gxb + (size_t)(b0 + w) * 12 * 4096 + head * 512;
    float gv[8];
#pragma unroll
    for (int q = 0; q < 8; q++) gv[q] = b2f(gbase[q * 64 + la]);   // step 0

    __syncthreads();

    for (int step = 0; step < 12; step++) {
        float gz0 = gv[0], gz1 = gv[1];
        float gi0 = gv[2], gi1 = gv[3];
        float gf0 = gv[4], gf1 = gv[5];
        float go0 = gv[6], go1 = gv[7];

        short8_t Af[4];
#pragma unroll
        for (int kk = 0; kk < 4; kk++)
            Af[kk] = *(const short8_t*)(sHb + l16 * HBP + kk * 32 + quad * 8);
        floatx4 D0 = (floatx4)0.f, D1 = (floatx4)0.f;
#pragma unroll
        for (int kk = 0; kk < 4; kk++) {
            D0 = __builtin_amdgcn_mfma_f32_16x16x32_bf16(Af[kk], Bf[0][kk], D0, 0, 0, 0);
            D1 = __builtin_amdgcn_mfma_f32_16x16x32_bf16(Af[kk], Bf[1][kk], D1, 0, 0, 0);
        }

        // ---- prefetch next step's gx (clamped index; unused at step 11).
        {
            const int sn = (step < 11) ? step + 1 : step;
            const unsigned short* gpn = gbase + (size_t)sn * 4096;
#pragma unroll
            for (int q = 0; q < 8; q++) gv[q] = b2f(gpn[q * 64 + la]);
        }

#pragma unroll
        for (int r = 0; r < 4; r++) {
            sRec[(quad * 4 + r) * RECP + w * 32 + l16] = D0[r];
            sRec[(quad * 4 + r) * RECP + w * 32 + 16 + l16] = D1[r];
        }
        __syncthreads();

        const float* rr = sRec + w * RECP;
        float zp0 = gz0 + rr[la],       zp1 = gz1 + rr[64 + la];
        float ip0 = gi0 + rr[128 + la], ip1 = gi1 + rr[192 + la];
        float fp0 = gf0 + rr[256 + la], fp1 = gf1 + rr[320 + la];
        float op0 = go0 + rr[384 + la], op1 = go1 + rr[448 + la];

        // tanh via sigmoid form + v_rcp (graceful at +/-inf preacts)
        float e20 = __expf(-2.f * zp0), e21 = __expf(-2.f * zp1);
        float z0 = 2.f * __builtin_amdgcn_rcpf(1.f + e20) - 1.f;
        float z1 = 2.f * __builtin_amdgcn_rcpf(1.f + e21) - 1.f;
        float o0 = __builtin_amdgcn_rcpf(1.f + __expf(-op0));
        float o1 = __builtin_amdgcn_rcpf(1.f + __expf(-op1));
        float mn0 = fmaxf(fp0 + m0, ip0), mn1 = fmaxf(fp1 + m1, ip1);
        float ie0 = __expf(ip0 - mn0), ie1 = __expf(ip1 - mn1);
        float fe0 = __expf(fp0 + m0 - mn0), fe1 = __expf(fp1 + m1 - mn1);
        c0 = fe0 * c0 + ie0 * z0;  c1 = fe1 * c1 + ie1 * z1;
        n0s = fe0 * n0s + ie0;     n1s = fe1 * n1s + ie1;
        m0 = mn0;                  m1 = mn1;
        float h0 = o0 * c0 * __builtin_amdgcn_rcpf(n0s);
        float h1 = o1 * c1 * __builtin_amdgcn_rcpf(n1s);

        float s = h0 + h1, ss = h0 * h0 + h1 * h1;
#pragma unroll
        for (int off = 32; off >= 1; off >>= 1) {
            s += __shfl_xor(s, off);
            ss += __shfl_xor(ss, off);
        }
        float mu = s * (1.f / 128.f);
        float var = ss * (1.f / 128.f) - mu * mu;
        float rs = rsqrtf(var + 1e-5f);
        size_t base = ((size_t)(b0 + w) * 12 + step) * 1024 + head * 128;
        hnb[base + la] = f2b((h0 - mu) * rs * gg0 + gb0);
        hnb[base + la + 64] = f2b((h1 - mu) * rs * gg1 + gb1);

        sHb[w * HBP + la] = f2b(h0);
        sHb[w * HBP + la + 64] = f2b(h1);
        __syncthreads();
    }
}

// ---------------- fused tail: conv1+gelu+LN(len)+conv2+skip ----------------
// R16 2-half structure (measured ~100us on healthy acquire, VGPR 56).

__global__ __launch_bounds__(512, 2) void tail_fused_kernel(
    const unsigned short* __restrict__ y, const float* __restrict__ skip,
    const float* __restrict__ w1, const float* __restrict__ b1,
    const float* __restrict__ w2, const float* __restrict__ b2,
    const float* __restrict__ lng, const float* __restrict__ lnb,
    float* __restrict__ out)
{
    __shared__ unsigned short sY[12][1026];   // 24.6 KB
    __shared__ unsigned short sZ[24][1026];   // 49.2 KB
    __shared__ float sMR[24][2];
    const int b = blockIdx.x;
    const int t = threadIdx.x;
    const int p = t;                          // positions p, p+512
    const size_t boff = (size_t)b * 12288;

    {
        const u32* gy = (const u32*)(y + boff);
#pragma unroll
        for (int ci = 0; ci < 12; ci++)
            ((u32*)&sY[ci][0])[t] = gy[ci * 512 + t];
    }
    // LN gains for the dword-mapped normalize pass (positions 2t, 2t+1)
    const float lgA = lng[2 * t], lbA = lnb[2 * t];
    const float lgB = lng[2 * t + 1], lbB = lnb[2 * t + 1];
    __syncthreads();

    float2_t acc[12];
#pragma unroll
    for (int o = 0; o < 12; o++) { float bv = b2[o]; acc[o] = float2_t{bv, bv}; }

    for (int h = 0; h < 2; h++) {
        // ---- conv1: 12 in -> this half's 24 out channels, ci-outer
        float2_t a1[24];
#pragma unroll
        for (int o = 0; o < 24; o++) {
            float bo = b1[h * 24 + o];
            a1[o] = float2_t{bo, bo};
        }
        for (int ci = 0; ci < 12; ci++) {
            float2_t v0 = float2_t{b2f(sY[ci][p]), b2f(sY[ci][p + 512])};
            float2_t vm = float2_t{(p > 0) ? b2f(sY[ci][p - 1]) : 0.f,
                                   b2f(sY[ci][p + 511])};
            float2_t vp = float2_t{b2f(sY[ci][p + 1]),
                                   (p < 511) ? b2f(sY[ci][p + 513]) : 0.f};
            const float* wp = w1 + ci * 3;             // uniform -> SGPR
#pragma unroll
            for (int o = 0; o < 24; o++) {
                const float* wo = wp + (h * 24 + o) * 36;
                a1[o] += vm * wo[0] + v0 * wo[1] + vp * wo[2];
            }
        }
#pragma unroll
        for (int o = 0; o < 24; o++) {
            sZ[o][p] = f2b(gelu_fast(a1[o].x));
            sZ[o][p + 512] = f2b(gelu_fast(a1[o].y));
        }
        __syncthreads();

        // ---- LN stats: wave wv handles ch wv, wv+8, wv+16
        {
            const int wv = t >> 6, la = t & 63;
#pragma unroll
            for (int j = 0; j < 3; j++) {
                const int ch = wv + j * 8;
                float s = 0.f, ss = 0.f;
#pragma unroll
                for (int u = 0; u < 8; u++) {
                    float2_t v = make2u(((const u32*)&sZ[ch][0])[la + u * 64]);
                    s += v.x + v.y;
                    ss += v.x * v.x + v.y * v.y;
                }
#pragma unroll
                for (int off = 32; off >= 1; off >>= 1) {
                    s += __shfl_xor(s, off);
                    ss += __shfl_xor(ss, off);
                }
                if (la == 0) {
                    float mu = s * (1.f / 1024.f);
                    float var = ss * (1.f / 1024.f) - mu * mu;
                    sMR[ch][0] = mu;
                    sMR[ch][1] = rsqrtf(var + 1e-5f);
                }
            }
        }
        __syncthreads();

        // ---- normalize in place (dword mapping: one b32 read+write per ch)
#pragma unroll
        for (int ch = 0; ch < 24; ch++) {
            const float mu = sMR[ch][0], rs = sMR[ch][1];
            float2_t f = make2u(((const u32*)&sZ[ch][0])[t]);
            f.x = (f.x - mu) * rs * lgA + lbA;
            f.y = (f.y - mu) * rs * lgB + lbB;
            ((u32*)&sZ[ch][0])[t] = pack2(f.x, f.y);
        }
        __syncthreads();

        // ---- conv2 partial over this half's 24 input channels
        for (int ci = 0; ci < 24; ci++) {
            float2_t z0 = float2_t{b2f(sZ[ci][p]), b2f(sZ[ci][p + 512])};
            float2_t zm = float2_t{(p > 0) ? b2f(sZ[ci][p - 1]) : 0.f,
                                   b2f(sZ[ci][p + 511])};
            float2_t zp = float2_t{b2f(sZ[ci][p + 1]),
                                   (p < 511) ? b2f(sZ[ci][p + 513]) : 0.f};
            const float* wp = w2 + (h * 24 + ci) * 3;  // uniform -> SGPR
#pragma unroll
            for (int o = 0; o < 12; o++)
                acc[o] += zm * wp[o * 144] + z0 * wp[o * 144 + 1]
                        + zp * wp[o * 144 + 2];
        }
        __syncthreads();   // before next half overwrites sZ
    }

#pragma unroll
    for (int o = 0; o < 12; o++) {
        size_t i0 = boff + (size_t)o * 1024 + p;
        out[i0] = acc[o].x + skip[i0];
        out[i0 + 512] = acc[o].y + skip[i0 + 512];
    }
}

// ------------------------------ launcher -----------------------------------

extern "C" void kernel_launch(void* const* d_in, const int* in_sizes, int n_in,
                              void* d_out, int out_size, void* d_ws, size_t ws_size,
                              hipStream_t stream)
{
    (void)in_sizes; (void)n_in; (void)out_size; (void)ws_size;
    const float* x      = (const float*)d_in[0];
    const float* ln_g   = (const float*)d_in[1];
    const float* ln_b   = (const float*)d_in[2];
    const float* fc1_w  = (const float*)d_in[3];
    const float* fc1_b  = (const float*)d_in[4];
    const float* fc2_w  = (const float*)d_in[5];
    const float* fc2_b  = (const float*)d_in[6];
    const float* conv1_w= (const float*)d_in[7];
    const float* conv1_b= (const float*)d_in[8];
    const float* conv2_w= (const float*)d_in[9];
    const float* conv2_b= (const float*)d_in[10];
    const float* xl_g   = (const float*)d_in[11];
    const float* xl_b   = (const float*)d_in[12];
    const float* Wg     = (const float*)d_in[13];
    const float* bg     = (const float*)d_in[14];
    const float* Rg     = (const float*)d_in[15];
    const float* gn_g   = (const float*)d_in[16];
    const float* gn_b   = (const float*)d_in[17];
    const float* upl_w  = (const float*)d_in[18];
    const float* upl_b  = (const float*)d_in[19];
    const float* upr_w  = (const float*)d_in[20];
    const float* upr_b  = (const float*)d_in[21];
    const float* down_w = (const float*)d_in[22];
    const float* down_b = (const float*)d_in[23];

    char* ws = (char*)d_ws;
    size_t off = 0;
    auto alloc = [&](size_t bytes) -> char* {
        char* p = ws + off;
        off = (off + bytes + 255) & ~(size_t)255;
        return p;
    };
    float* xn            = (float*)alloc(25165824);          // 6144x1024 f32
    unsigned short* xcb  = (unsigned short*)alloc(12582912); // 6144x1024 bf16
    unsigned short* x1b  = (unsigned short*)alloc(12582912);
    unsigned short* xn2b = (unsigned short*)alloc(12582912);
    unsigned short* gxb  = (unsigned short*)alloc(50331648); // 6144x4096 bf16
    unsigned short* hnb  = (unsigned short*)alloc(12582912);
    unsigned short* glrb = (unsigned short*)alloc(12582912); // 6144x1024 bf16
    unsigned short* yb   = (unsigned short*)alloc(12582912); // 6144x1024 bf16
    unsigned short* WgT  = (unsigned short*)alloc(8388608);  // 4096x1024 bf16
    unsigned short* WupT = (unsigned short*)alloc(4194304);  // 2048x1024 bf16 (interleaved)
    unsigned short* WdT  = (unsigned short*)alloc(2097152);  // 1024x1024 bf16
    float* bup           = (float*)alloc(8192);              // 2048 f32 (interleaved)

    // weight prep (merged: 4 transposes + bias interleave in one dispatch)
    prep_weights_kernel<<<dim3(232, 32), 256, 0, stream>>>(
        Wg, upl_w, upr_w, down_w, upl_b, upr_b, WgT, WupT, WdT, bup);

    // main pipeline
    ln_fc_kernel<<<512, 512, 0, stream>>>(
        x, ln_g, ln_b, xl_g, xl_b, fc1_w, fc1_b, fc2_w, fc2_b,
        xn, xcb, x1b, xn2b);
    gemm_kernel<0><<<dim3(32, 48), 256, 0, stream>>>(
        xn2b, WgT, bg, gxb, 6144, 4096, 1024, nullptr, nullptr, nullptr);
    slstm_rec_kernel<<<dim3(8, 32), 1024, 0, stream>>>(Rg, gxb, gn_g, gn_b, hnb);
    gemm_kernel<3><<<dim3(16, 48), 256, 0, stream>>>(
        hnb, WupT, bup, glrb, 6144, 2048, 1024, nullptr, nullptr, nullptr);
    gemm_kernel<2><<<dim3(8, 48), 256, 0, stream>>>(
        glrb, WdT, down_b, yb, 6144, 1024, 1024, xcb, x1b, xn);
    tail_fused_kernel<<<512, 512, 0, stream>>>(
        yb, xn, conv1_w, conv1_b, conv2_w, conv2_b, ln_g, ln_b, (float*)d_out);
}